// Round 1
// baseline (2388.852 us; speedup 1.0000x reference)
//
#include <hip/hip_runtime.h>
#include <math.h>

#define Bq 16
#define Lq 2048
#define Hq 256
#define Nst 64
#define LC 128
#define NC 16      // Lq / LC
#define NL 4
#define SZ ((size_t)Bq * Lq * Hq)   // 8388608

// ---------------- param kernels ----------------
// per (h,n): w = exp(dtA), w65 = w^65, wLc = w^128, Cd = C*(w-1)/A
__global__ __launch_bounds__(256) void paramA_k(
    const float* __restrict__ log_dt, const float* __restrict__ Alog,
    const float* __restrict__ Aim, const float* __restrict__ Cre,
    const float* __restrict__ Cim,
    float* __restrict__ wv, float* __restrict__ wLc,
    float* __restrict__ w65, float* __restrict__ Cd) {
  int i = blockIdx.x * blockDim.x + threadIdx.x;   // h*Nst + n
  if (i >= Hq * Nst) return;
  int h = i >> 6;
  float dt = expf(log_dt[h]);
  float ar = -expf(Alog[i]);
  float ai = Aim[i];
  float dr = ar * dt, di = ai * dt;
  float er = expf(dr); float sn, cs; sincosf(di, &sn, &cs);
  float wr = er * cs, wi = er * sn;
  wv[2*i] = wr; wv[2*i+1] = wi;
  float e2 = expf(dr * (float)LC); float sn2, cs2; sincosf(di * (float)LC, &sn2, &cs2);
  wLc[2*i] = e2 * cs2; wLc[2*i+1] = e2 * sn2;
  float e3 = expf(dr * 65.f); float sn3, cs3; sincosf(di * 65.f, &sn3, &cs3);
  w65[2*i] = e3 * cs3; w65[2*i+1] = e3 * sn3;
  // Cd = C * (w-1)/A
  float nr = wr - 1.f, ni = wi;
  float d2 = ar*ar + ai*ai;
  float qr = (nr*ar + ni*ai) / d2;
  float qi = (ni*ar - nr*ai) / d2;
  float cr = Cre[i], ci = Cim[i];
  Cd[2*i]   = cr*qr - ci*qi;
  Cd[2*i+1] = cr*qi + ci*qr;
}

// Ktaps[h][m] = 2*Re(sum_n Cd * w^m), m in [0,128). One wave per h, lane = n.
__global__ __launch_bounds__(64) void paramB_k(
    const float* __restrict__ wv, const float* __restrict__ Cd,
    float* __restrict__ Kt) {
  int h = blockIdx.x, n = threadIdx.x;
  int i = h * Nst + n;
  float wr = wv[2*i], wi = wv[2*i+1];
  float cr = Cd[2*i], ci = Cd[2*i+1];
  float pr = 1.f, pi = 0.f;
  for (int m = 0; m < LC; ++m) {
    float v = 2.f * (cr*pr - ci*pi);
    for (int off = 32; off; off >>= 1) v += __shfl_down(v, off);
    if (n == 0) Kt[h * LC + m] = v;
    float t = pr*wr - pi*wi;
    pi = fmaf(pr, wi, pi*wr);
    pr = t;
  }
}

// ---------------- layernorm (over H, per (b,l) row) ----------------
__global__ __launch_bounds__(256) void ln_k(
    const float* __restrict__ hb, const float* __restrict__ sc,
    const float* __restrict__ bi, float* __restrict__ zn) {
  int row = blockIdx.x * 4 + (threadIdx.x >> 6);
  int lane = threadIdx.x & 63;
  const float4 v = ((const float4*)(hb + (size_t)row * Hq))[lane];
  float s  = v.x + v.y + v.z + v.w;
  float s2 = v.x*v.x + v.y*v.y + v.z*v.z + v.w*v.w;
  for (int off = 32; off; off >>= 1) { s += __shfl_down(s, off); s2 += __shfl_down(s2, off); }
  s = __shfl(s, 0); s2 = __shfl(s2, 0);
  float mu = s * (1.f / Hq);
  float var = s2 * (1.f / Hq) - mu * mu;
  float r = rsqrtf(var + 1e-5f);
  float4 scv = ((const float4*)sc)[lane];
  float4 biv = ((const float4*)bi)[lane];
  float4 o;
  o.x = (v.x - mu) * r * scv.x + biv.x;
  o.y = (v.y - mu) * r * scv.y + biv.y;
  o.z = (v.z - mu) * r * scv.z + biv.z;
  o.w = (v.w - mu) * r * scv.w + biv.w;
  ((float4*)(zn + (size_t)row * Hq))[lane] = o;
}

// ---------------- pass1: per-chunk local state sums ----------------
// S_local[b,c,h,n] = sum_{j=0..127} w^(127-j) * u[b, c*128+j, h]
__global__ __launch_bounds__(1024) void pass1_k(
    const float* __restrict__ zn, const float* __restrict__ wv,
    float* __restrict__ S) {
  int bc = blockIdx.x >> 1;
  int hg = blockIdx.x & 1;         // 128-h half
  int b = bc >> 4, c = bc & 15;
  __shared__ float u[LC][128];     // 64KB
  const float* src = zn + ((size_t)(b * Lq + c * LC)) * Hq + hg * 128;
  for (int idx = threadIdx.x; idx < LC * 128; idx += 1024) {
    int j = idx >> 7, hh = idx & 127;
    u[j][hh] = src[(size_t)j * Hq + hh];
  }
  __syncthreads();
  int hh = threadIdx.x >> 3;       // 0..127
  int nl = threadIdx.x & 7;        // 0..7
  int h = hg * 128 + hh;
  for (int k = 0; k < 8; ++k) {
    int n = nl * 8 + k;
    int i = h * Nst + n;
    float wr = wv[2*i], wi = wv[2*i+1];
    float pr = 1.f, pi = 0.f, sr = 0.f, si = 0.f;
    for (int j = LC - 1; j >= 0; --j) {
      float uu = u[j][hh];
      sr = fmaf(pr, uu, sr);
      si = fmaf(pi, uu, si);
      float t = pr*wr - pi*wi;
      pi = fmaf(pr, wi, pi*wr);
      pr = t;
    }
    size_t o = ((((size_t)b * NC + c) * Hq + h) * Nst + n) * 2;
    S[o] = sr; S[o+1] = si;
  }
}

// ---------------- scan over chunks (inclusive) ----------------
__global__ __launch_bounds__(256) void scan_k(float* __restrict__ S,
                                              const float* __restrict__ wLc) {
  int i = blockIdx.x * blockDim.x + threadIdx.x;   // b*(H*N) + hn
  if (i >= Bq * Hq * Nst) return;
  int hn = i % (Hq * Nst);
  int b  = i / (Hq * Nst);
  float wr = wLc[2*hn], wi = wLc[2*hn+1];
  float sr = 0.f, si = 0.f;
  for (int c = 0; c < NC; ++c) {
    size_t o = (((size_t)b * NC + c) * (Hq * Nst) + hn) * 2;
    float ar = S[o], ai = S[o+1];
    float nr2 = fmaf(wr, sr, fmaf(-wi, si, ar));
    float ni2 = fmaf(wr, si, fmaf( wi, sr, ai));
    S[o] = nr2; S[o+1] = ni2;
    sr = nr2; si = ni2;
  }
}

// ---------------- pass3a: cross-chunk correction ----------------
// corr[b, c*128 + t0 + t, h] = 2*Re(sum_n Cd * w^(t0+t+1) * S[b,c-1,h,n])
__global__ __launch_bounds__(256) void pass3a_k(
    const float* __restrict__ S, const float* __restrict__ wv,
    const float* __restrict__ w65, const float* __restrict__ Cd,
    float* __restrict__ yb) {
  int th = blockIdx.x & 1;         // t-half: t0 = th*64
  int bc = blockIdx.x >> 1;
  int b = bc >> 4, c = bc & 15;
  int h = threadIdx.x;
  __shared__ float corr[Hq][64];   // 64KB, XOR-swizzled on t -> conflict-free
  int sw = h & 31;
  #pragma unroll
  for (int t = 0; t < 64; ++t) corr[h][t ^ sw] = 0.f;   // own row only: no sync needed
  if (c > 0) {
    size_t spb = (((size_t)b * NC + (c - 1)) * Hq + h) * (size_t)Nst * 2;
    for (int nc = 0; nc < 8; ++nc) {
      float qr[8], qi[8], wr[8], wi[8];
      #pragma unroll
      for (int i = 0; i < 8; ++i) {
        int n = nc * 8 + i;
        int idx = h * Nst + n;
        wr[i] = wv[2*idx]; wi[i] = wv[2*idx+1];
        float br = (th == 0) ? wr[i] : w65[2*idx];
        float bi = (th == 0) ? wi[i] : w65[2*idx+1];
        float cr = Cd[2*idx], ci = Cd[2*idx+1];
        float sr = S[spb + 2*n], si = S[spb + 2*n + 1];
        float tr = cr*sr - ci*si, ti = cr*si + ci*sr;   // Cd*Sp
        qr[i] = tr*br - ti*bi;                           // *w^(t0+1)
        qi[i] = tr*bi + ti*br;
      }
      for (int t = 0; t < 64; ++t) {
        float acc = 0.f;
        #pragma unroll
        for (int i = 0; i < 8; ++i) {
          acc += qr[i];
          float tq = qr[i]*wr[i] - qi[i]*wi[i];
          qi[i] = fmaf(qr[i], wi[i], qi[i]*wr[i]);
          qr[i] = tq;
        }
        corr[h][t ^ sw] += 2.f * acc;
      }
    }
  }
  int l0 = c * LC + th * 64;
  for (int t = 0; t < 64; ++t)
    yb[((size_t)b * Lq + l0 + t) * Hq + h] = corr[h][t ^ sw];
}

// ---------------- pass3b: within-chunk Toeplitz conv + D*u + GELU ----------------
__global__ __launch_bounds__(512) void pass3b_k(
    const float* __restrict__ zn, const float* __restrict__ Kt,
    const float* __restrict__ Dv, float* __restrict__ yb) {
  int hg = blockIdx.x & 3;         // 64-h group
  int bc = blockIdx.x >> 2;
  int b = bc >> 4, c = bc & 15;
  __shared__ float u[LC][64];      // 32KB
  __shared__ float kt[64][LC];     // 32KB, XOR-swizzled on m
  const float* src = zn + ((size_t)(b * Lq + c * LC)) * Hq + hg * 64;
  for (int idx = threadIdx.x; idx < LC * 64; idx += 512) {
    int j = idx >> 6, hh = idx & 63;
    u[j][hh] = src[(size_t)j * Hq + hh];
  }
  for (int idx = threadIdx.x; idx < 64 * LC; idx += 512) {
    int hh = idx >> 7, m = idx & 127;
    kt[hh][m ^ (hh & 31)] = Kt[(hg * 64 + hh) * LC + m];
  }
  __syncthreads();
  int tl = threadIdx.x >> 6;       // 0..7 (uniform t per wave)
  int hh = threadIdx.x & 63;
  int h = hg * 64 + hh;
  float dv = Dv[h];
  int sw = hh & 31;
  for (int k = 0; k < 16; ++k) {
    int t = tl + 8 * k;
    size_t gofs = ((size_t)b * Lq + c * LC + t) * Hq + h;
    float acc = yb[gofs];                 // correction from pass3a
    acc = fmaf(dv, u[t][hh], acc);        // D * u
    for (int j = 0; j <= t; ++j)
      acc = fmaf(kt[hh][(t - j) ^ sw], u[j][hh], acc);
    // gelu (tanh approx, jax default)
    float x = acc;
    float inner = 0.7978845608028654f * fmaf(0.044715f, x*x*x, x);
    float g = 0.5f * x * (1.f + tanhf(inner));
    yb[gofs] = g;
  }
}

// ---------------- GEMM (32768 x 256 x 512) + bias + GLU + residual ----------------
__global__ __launch_bounds__(256) void gemm_k(
    const float* __restrict__ yb, const float* __restrict__ Wout,
    const float* __restrict__ bout, float* __restrict__ hb) {
  int rt = blockIdx.x;             // 512 row tiles of 64 (b,l) rows
  int ot = blockIdx.y;             // 8 o-tiles of 32 (paired with o+256)
  __shared__ float2 yt[64][64];    // 32KB
  __shared__ float2 w1[32][64];    // 16KB
  __shared__ float2 w2[32][64];    // 16KB
  int ti = threadIdx.x >> 4, tj = threadIdx.x & 15;
  float acc1[4][2] = {{0.f,0.f},{0.f,0.f},{0.f,0.f},{0.f,0.f}};
  float acc2[4][2] = {{0.f,0.f},{0.f,0.f},{0.f,0.f},{0.f,0.f}};
  for (int kc = 0; kc < 2; ++kc) {
    for (int idx = threadIdx.x; idx < 64 * 64; idx += 256) {
      int r = idx >> 6, k2 = idx & 63;
      yt[r][k2 ^ (r & 31)] =
          *(const float2*)(yb + (size_t)(rt * 64 + r) * Hq + kc * 128 + k2 * 2);
    }
    for (int idx = threadIdx.x; idx < 32 * 64; idx += 256) {
      int o = idx >> 6, k2 = idx & 63;
      w1[o][k2 ^ (o & 31)] =
          *(const float2*)(Wout + (size_t)(ot * 32 + o) * Hq + kc * 128 + k2 * 2);
      w2[o][k2 ^ (o & 31)] =
          *(const float2*)(Wout + (size_t)(ot * 32 + o + 256) * Hq + kc * 128 + k2 * 2);
    }
    __syncthreads();
    for (int k2 = 0; k2 < 64; ++k2) {
      float2 ya[4], wa[2], wb[2];
      #pragma unroll
      for (int r = 0; r < 4; ++r) ya[r] = yt[ti*4 + r][k2 ^ ((ti*4 + r) & 31)];
      #pragma unroll
      for (int o = 0; o < 2; ++o) {
        wa[o] = w1[tj*2 + o][k2 ^ ((tj*2 + o) & 31)];
        wb[o] = w2[tj*2 + o][k2 ^ ((tj*2 + o) & 31)];
      }
      #pragma unroll
      for (int r = 0; r < 4; ++r)
        #pragma unroll
        for (int o = 0; o < 2; ++o) {
          acc1[r][o] = fmaf(ya[r].x, wa[o].x, fmaf(ya[r].y, wa[o].y, acc1[r][o]));
          acc2[r][o] = fmaf(ya[r].x, wb[o].x, fmaf(ya[r].y, wb[o].y, acc2[r][o]));
        }
    }
    __syncthreads();
  }
  #pragma unroll
  for (int r = 0; r < 4; ++r) {
    size_t R = (size_t)rt * 64 + ti * 4 + r;
    #pragma unroll
    for (int o = 0; o < 2; ++o) {
      int og = ot * 32 + tj * 2 + o;
      float z1 = acc1[r][o] + bout[og];
      float z2 = acc2[r][o] + bout[og + 256];
      float g = z1 * (1.f / (1.f + expf(-z2)));
      size_t idx = R * Hq + og;
      hb[idx] = g + hb[idx];     // GLU + residual, in place
    }
  }
}

extern "C" void kernel_launch(void* const* d_in, const int* in_sizes, int n_in,
                              void* d_out, int out_size, void* d_ws, size_t ws_size,
                              hipStream_t stream) {
  (void)in_sizes; (void)n_in; (void)out_size; (void)ws_size;
  const float* x      = (const float*)d_in[0];
  const float* log_dt = (const float*)d_in[1];
  const float* Alog   = (const float*)d_in[2];
  const float* Aim    = (const float*)d_in[3];
  const float* Cre    = (const float*)d_in[4];
  const float* Cim    = (const float*)d_in[5];
  const float* Dv     = (const float*)d_in[6];
  const float* Wout   = (const float*)d_in[7];
  const float* bout   = (const float*)d_in[8];
  const float* lns    = (const float*)d_in[9];
  const float* lnb    = (const float*)d_in[10];

  float* hb = (float*)d_out;       // running h, layout (B, L, H)
  float* ws = (float*)d_ws;
  float* zn  = ws;                 // LN output          (B,L,H)
  float* yb  = ws + SZ;            // conv output        (B,L,H)
  float* S   = ws + 2 * SZ;        // chunk states       (B,NC,H,N) cplx
  float* wv  = ws + 3 * SZ;        // w                  (H,N) cplx
  float* wLc = wv  + 2 * Hq * Nst; // w^128
  float* w65 = wLc + 2 * Hq * Nst; // w^65
  float* Cd  = w65 + 2 * Hq * Nst; // Cd
  float* Kt  = Cd  + 2 * Hq * Nst; // kernel taps (H,128)

  hipMemcpyAsync(hb, x, SZ * sizeof(float), hipMemcpyDeviceToDevice, stream);

  for (int i = 0; i < NL; ++i) {
    paramA_k<<<(Hq * Nst) / 256, 256, 0, stream>>>(
        log_dt + i * Hq, Alog + (size_t)i * Hq * Nst, Aim + (size_t)i * Hq * Nst,
        Cre + (size_t)i * Hq * Nst, Cim + (size_t)i * Hq * Nst, wv, wLc, w65, Cd);
    paramB_k<<<Hq, 64, 0, stream>>>(wv, Cd, Kt);
    ln_k<<<(Bq * Lq) / 4, 256, 0, stream>>>(hb, lns + i * Hq, lnb + i * Hq, zn);
    pass1_k<<<Bq * NC * 2, 1024, 0, stream>>>(zn, wv, S);
    scan_k<<<(Bq * Hq * Nst) / 256, 256, 0, stream>>>(S, wLc);
    pass3a_k<<<Bq * NC * 2, 256, 0, stream>>>(S, wv, w65, Cd, yb);
    pass3b_k<<<Bq * NC * 4, 512, 0, stream>>>(zn, Kt, Dv + i * Hq, yb);
    gemm_k<<<dim3((Bq * Lq) / 64, Hq / 32), 256, 0, stream>>>(
        yb, Wout + (size_t)i * 2 * Hq * Hq, bout + (size_t)i * 2 * Hq, hb);
  }
}

// Round 2
// 1614.913 us; speedup vs baseline: 1.4792x; 1.4792x over previous
//
#include <hip/hip_runtime.h>
#include <hip/hip_bf16.h>
#include <math.h>

#define Bq 16
#define Lq 2048
#define Hq 256
#define Nst 64
#define LC 128
#define NC 16      // Lq / LC
#define NL 4
#define GK 256     // GEMM K = Hq
#define SZ ((size_t)Bq * Lq * Hq)   // 8388608

typedef __attribute__((ext_vector_type(8))) short short8;  // 8 bf16 (4 VGPRs)
typedef __attribute__((ext_vector_type(4))) float f32x4;

__device__ inline void gload16(const void* g, void* l) {
  __builtin_amdgcn_global_load_lds(
      (const __attribute__((address_space(1))) void*)g,
      (__attribute__((address_space(3))) void*)l, 16, 0, 0);
}

// ---------------- param kernels ----------------
__global__ __launch_bounds__(256) void paramA_k(
    const float* __restrict__ log_dt, const float* __restrict__ Alog,
    const float* __restrict__ Aim, const float* __restrict__ Cre,
    const float* __restrict__ Cim,
    float* __restrict__ wv, float* __restrict__ wLc,
    float* __restrict__ w65, float* __restrict__ Cd) {
  int i = blockIdx.x * blockDim.x + threadIdx.x;   // h*Nst + n
  if (i >= Hq * Nst) return;
  int h = i >> 6;
  float dt = expf(log_dt[h]);
  float ar = -expf(Alog[i]);
  float ai = Aim[i];
  float dr = ar * dt, di = ai * dt;
  float er = expf(dr); float sn, cs; sincosf(di, &sn, &cs);
  float wr = er * cs, wi = er * sn;
  wv[2*i] = wr; wv[2*i+1] = wi;
  float e2 = expf(dr * (float)LC); float sn2, cs2; sincosf(di * (float)LC, &sn2, &cs2);
  wLc[2*i] = e2 * cs2; wLc[2*i+1] = e2 * sn2;
  float e3 = expf(dr * 65.f); float sn3, cs3; sincosf(di * 65.f, &sn3, &cs3);
  w65[2*i] = e3 * cs3; w65[2*i+1] = e3 * sn3;
  float nr = wr - 1.f, ni = wi;
  float d2 = ar*ar + ai*ai;
  float qr = (nr*ar + ni*ai) / d2;
  float qi = (ni*ar - nr*ai) / d2;
  float cr = Cre[i], ci = Cim[i];
  Cd[2*i]   = cr*qr - ci*qi;
  Cd[2*i+1] = cr*qi + ci*qr;
}

// Ktaps[h][m] = 2*Re(sum_n Cd * w^m)
__global__ __launch_bounds__(64) void paramB_k(
    const float* __restrict__ wv, const float* __restrict__ Cd,
    float* __restrict__ Kt) {
  int h = blockIdx.x, n = threadIdx.x;
  int i = h * Nst + n;
  float wr = wv[2*i], wi = wv[2*i+1];
  float cr = Cd[2*i], ci = Cd[2*i+1];
  float pr = 1.f, pi = 0.f;
  for (int m = 0; m < LC; ++m) {
    float v = 2.f * (cr*pr - ci*pi);
    for (int off = 32; off; off >>= 1) v += __shfl_down(v, off);
    if (n == 0) Kt[h * LC + m] = v;
    float t = pr*wr - pi*wi;
    pi = fmaf(pr, wi, pi*wr);
    pr = t;
  }
}

// ---------------- W -> bf16 ----------------
__global__ __launch_bounds__(256) void cvtw_k(
    const float* __restrict__ w, __hip_bfloat16* __restrict__ wb, int n) {
  int i = blockIdx.x * 256 + threadIdx.x;
  if (i < n) wb[i] = __float2bfloat16(w[i]);
}

// ---------------- layernorm ----------------
__global__ __launch_bounds__(256) void ln_k(
    const float* __restrict__ hb, const float* __restrict__ sc,
    const float* __restrict__ bi, float* __restrict__ zn) {
  int row = blockIdx.x * 4 + (threadIdx.x >> 6);
  int lane = threadIdx.x & 63;
  const float4 v = ((const float4*)(hb + (size_t)row * Hq))[lane];
  float s  = v.x + v.y + v.z + v.w;
  float s2 = v.x*v.x + v.y*v.y + v.z*v.z + v.w*v.w;
  for (int off = 32; off; off >>= 1) { s += __shfl_down(s, off); s2 += __shfl_down(s2, off); }
  s = __shfl(s, 0); s2 = __shfl(s2, 0);
  float mu = s * (1.f / Hq);
  float var = s2 * (1.f / Hq) - mu * mu;
  float r = rsqrtf(var + 1e-5f);
  float4 scv = ((const float4*)sc)[lane];
  float4 biv = ((const float4*)bi)[lane];
  float4 o;
  o.x = (v.x - mu) * r * scv.x + biv.x;
  o.y = (v.y - mu) * r * scv.y + biv.y;
  o.z = (v.z - mu) * r * scv.z + biv.z;
  o.w = (v.w - mu) * r * scv.w + biv.w;
  ((float4*)(zn + (size_t)row * Hq))[lane] = o;
}

// ---------------- pass1: per-chunk local state sums ----------------
// S_local[b,c,h,n] = sum_j w^(127-j) u[b,c*128+j,h] via ascending recurrence s=w*s+u
__global__ __launch_bounds__(1024) void pass1_k(
    const float* __restrict__ zn, const float* __restrict__ wv,
    float* __restrict__ S) {
  int bc = blockIdx.x >> 1;
  int hg = blockIdx.x & 1;
  int b = bc >> 4, c = bc & 15;
  __shared__ float u[LC][128];
  const float* src = zn + ((size_t)(b * Lq + c * LC)) * Hq + hg * 128;
  for (int idx = threadIdx.x; idx < LC * 128; idx += 1024) {
    int j = idx >> 7, hh = idx & 127;
    u[j][hh] = src[(size_t)j * Hq + hh];
  }
  __syncthreads();
  int hh = threadIdx.x >> 3;
  int nl = threadIdx.x & 7;
  int h = hg * 128 + hh;
  float wr[8], wi[8], sr[8], si[8];
  #pragma unroll
  for (int i = 0; i < 8; ++i) {
    int idx = h * Nst + nl * 8 + i;
    wr[i] = wv[2*idx]; wi[i] = wv[2*idx+1];
    sr[i] = 0.f; si[i] = 0.f;
  }
  for (int j = 0; j < LC; ++j) {
    float uu = u[j][hh];
    #pragma unroll
    for (int i = 0; i < 8; ++i) {
      float t1 = fmaf(-wi[i], si[i], uu);
      float t2 = wi[i] * sr[i];
      sr[i] = fmaf(wr[i], sr[i], t1);
      si[i] = fmaf(wr[i], si[i], t2);
    }
  }
  #pragma unroll
  for (int i = 0; i < 8; ++i) {
    size_t o = ((((size_t)b * NC + c) * Hq + h) * Nst + nl * 8 + i) * 2;
    S[o] = sr[i]; S[o+1] = si[i];
  }
}

// ---------------- scan over chunks ----------------
__global__ __launch_bounds__(256) void scan_k(float* __restrict__ S,
                                              const float* __restrict__ wLc) {
  int i = blockIdx.x * blockDim.x + threadIdx.x;
  if (i >= Bq * Hq * Nst) return;
  int hn = i % (Hq * Nst);
  int b  = i / (Hq * Nst);
  float wr = wLc[2*hn], wi = wLc[2*hn+1];
  float sr = 0.f, si = 0.f;
  for (int c = 0; c < NC; ++c) {
    size_t o = (((size_t)b * NC + c) * (Hq * Nst) + hn) * 2;
    float ar = S[o], ai = S[o+1];
    float nr2 = fmaf(wr, sr, fmaf(-wi, si, ar));
    float ni2 = fmaf(wr, si, fmaf( wi, sr, ai));
    S[o] = nr2; S[o+1] = ni2;
    sr = nr2; si = ni2;
  }
}

// ---------------- pass3a: cross-chunk correction ----------------
__global__ __launch_bounds__(256) void pass3a_k(
    const float* __restrict__ S, const float* __restrict__ wv,
    const float* __restrict__ w65, const float* __restrict__ Cd,
    float* __restrict__ ybc) {
  int th = blockIdx.x & 1;
  int bc = blockIdx.x >> 1;
  int b = bc >> 4, c = bc & 15;
  int h = threadIdx.x;
  __shared__ float corr[Hq][64];
  int sw = h & 31;
  #pragma unroll
  for (int t = 0; t < 64; ++t) corr[h][t ^ sw] = 0.f;
  if (c > 0) {
    size_t spb = (((size_t)b * NC + (c - 1)) * Hq + h) * (size_t)Nst * 2;
    for (int nc = 0; nc < 8; ++nc) {
      float qr[8], qi[8], wr[8], wi[8];
      #pragma unroll
      for (int i = 0; i < 8; ++i) {
        int n = nc * 8 + i;
        int idx = h * Nst + n;
        wr[i] = wv[2*idx]; wi[i] = wv[2*idx+1];
        float br = (th == 0) ? wr[i] : w65[2*idx];
        float bi = (th == 0) ? wi[i] : w65[2*idx+1];
        float cr = Cd[2*idx], ci = Cd[2*idx+1];
        float sr = S[spb + 2*n], si = S[spb + 2*n + 1];
        float tr = cr*sr - ci*si, ti = cr*si + ci*sr;
        qr[i] = tr*br - ti*bi;
        qi[i] = tr*bi + ti*br;
      }
      for (int t = 0; t < 64; ++t) {
        float acc = 0.f;
        #pragma unroll
        for (int i = 0; i < 8; ++i) {
          acc += qr[i];
          float tq = qr[i]*wr[i] - qi[i]*wi[i];
          qi[i] = fmaf(qr[i], wi[i], qi[i]*wr[i]);
          qr[i] = tq;
        }
        corr[h][t ^ sw] += 2.f * acc;
      }
    }
  }
  int l0 = c * LC + th * 64;
  for (int t = 0; t < 64; ++t)
    ybc[((size_t)b * Lq + l0 + t) * Hq + h] = corr[h][t ^ sw];
}

// ---------------- pass3b: Toeplitz conv + D*u + GELU -> bf16 ----------------
// thread (hh, tl): 16 interleaved t's (t = tl + 8r) in registers; u read once/j
__global__ __launch_bounds__(512) void pass3b_k(
    const float* __restrict__ zn, const float* __restrict__ Kt,
    const float* __restrict__ Dv, const float* __restrict__ ybc,
    __hip_bfloat16* __restrict__ ybb) {
  int hg = blockIdx.x & 3;
  int bc = blockIdx.x >> 2;
  int b = bc >> 4, c = bc & 15;
  __shared__ float u[LC][64];      // 32KB, conflict-free by construction
  __shared__ float kt2[LC][65];    // taps transposed + pad -> conflict-free
  const float* src = zn + ((size_t)(b * Lq + c * LC)) * Hq + hg * 64;
  for (int idx = threadIdx.x; idx < LC * 64; idx += 512) {
    int j = idx >> 6, hh = idx & 63;
    u[j][hh] = src[(size_t)j * Hq + hh];
  }
  for (int idx = threadIdx.x; idx < 64 * LC; idx += 512) {
    int hh = idx >> 7, d = idx & 127;
    kt2[d][hh] = Kt[(hg * 64 + hh) * LC + d];
  }
  __syncthreads();
  int tl = threadIdx.x >> 6;       // wave id: uniform
  int hh = threadIdx.x & 63;
  int h = hg * 64 + hh;
  float dv = Dv[h];
  size_t base = ((size_t)b * Lq + c * LC + tl) * Hq + h;
  float acc[16];
  #pragma unroll
  for (int r = 0; r < 16; ++r) {
    int t = tl + 8 * r;
    acc[r] = ybc[base + (size_t)(8 * r) * Hq] + dv * u[t][hh];
  }
  for (int j = 0; j < LC; ++j) {
    float uu = u[j][hh];
    int mj = tl - j;
    #pragma unroll
    for (int r = 0; r < 16; ++r) {
      int m = mj + 8 * r;
      if (m >= 0) acc[r] = fmaf(kt2[m][hh], uu, acc[r]);   // wave-uniform guard
    }
  }
  #pragma unroll
  for (int r = 0; r < 16; ++r) {
    float x = acc[r];
    float inner = 0.7978845608028654f * fmaf(0.044715f, x*x*x, x);
    float g = 0.5f * x * (1.f + tanhf(inner));
    ybb[base + (size_t)(8 * r) * Hq] = __float2bfloat16(g);
  }
}

// ---------------- bf16 MFMA GEMM + bias + GLU + residual ----------------
// M=32768 (bl), K=256 (h), logical N=256 GLU pairs (physical 512 W rows).
// Block: 128 M x 64 pairs (=128 phys cols: col<64 -> o, col>=64 -> o+256).
// 4 waves, wave w owns rows [w*32, w*32+32) x all 128 cols.
__global__ __launch_bounds__(256) void gemm_k(
    const __hip_bfloat16* __restrict__ ybb, const __hip_bfloat16* __restrict__ Wb,
    const float* __restrict__ bout, float* __restrict__ hb) {
  __shared__ __hip_bfloat16 As[128 * 64];   // [row][64k] linear, src pre-swizzled
  __shared__ __hip_bfloat16 Bs[128 * 64];
  int tid = threadIdx.x;
  int m0 = blockIdx.x * 128;
  int ot = blockIdx.y;             // 0..3
  int wid = tid >> 6, lane = tid & 63;
  int cl = lane & 15, kq = lane >> 4;
  f32x4 acc[2][8] = {};
  for (int kt = 0; kt < GK / 64; ++kt) {
    int k0 = kt * 64;
    #pragma unroll
    for (int q = 0; q < 4; ++q) {
      int idx = q * 256 + tid;
      int r = idx >> 3, ch = idx & 7;
      const __hip_bfloat16* sA =
          ybb + (size_t)(m0 + r) * GK + k0 + ((ch ^ (r & 7)) << 3);
      gload16(sA, (char*)As + (size_t)(q * 256 + (tid & ~63)) * 16);
      int wrow = ot * 64 + r + ((r >= 64) ? 192 : 0);
      const __hip_bfloat16* sB =
          Wb + (size_t)wrow * GK + k0 + ((ch ^ (r & 7)) << 3);
      gload16(sB, (char*)Bs + (size_t)(q * 256 + (tid & ~63)) * 16);
    }
    __syncthreads();
    #pragma unroll
    for (int kk = 0; kk < 2; ++kk) {
      short8 a[2], bfr[8];
      #pragma unroll
      for (int mi = 0; mi < 2; ++mi) {
        int m = wid * 32 + mi * 16 + cl;
        int ch = (kk * 4 + kq) ^ (m & 7);
        a[mi] = *(const short8*)(As + m * 64 + ch * 8);
      }
      #pragma unroll
      for (int ni = 0; ni < 8; ++ni) {
        int n = ni * 16 + cl;
        int ch = (kk * 4 + kq) ^ (n & 7);
        bfr[ni] = *(const short8*)(Bs + n * 64 + ch * 8);
      }
      #pragma unroll
      for (int mi = 0; mi < 2; ++mi)
        #pragma unroll
        for (int ni = 0; ni < 8; ++ni)
          acc[mi][ni] = __builtin_amdgcn_mfma_f32_16x16x32_bf16(
              a[mi], bfr[ni], acc[mi][ni], 0, 0, 0);
    }
    __syncthreads();
  }
  // epilogue: C/D layout col=lane&15, row=(lane>>4)*4+reg
  #pragma unroll
  for (int mi = 0; mi < 2; ++mi) {
    #pragma unroll
    for (int ni = 0; ni < 4; ++ni) {
      int o1 = ot * 64 + ni * 16 + cl;
      float b1 = bout[o1], b2 = bout[o1 + 256];
      #pragma unroll
      for (int r = 0; r < 4; ++r) {
        int row = m0 + wid * 32 + mi * 16 + kq * 4 + r;
        float z1 = acc[mi][ni][r] + b1;
        float z2 = acc[mi][ni + 4][r] + b2;
        float g = z1 / (1.f + expf(-z2));
        hb[(size_t)row * Hq + o1] += g;
      }
    }
  }
}

extern "C" void kernel_launch(void* const* d_in, const int* in_sizes, int n_in,
                              void* d_out, int out_size, void* d_ws, size_t ws_size,
                              hipStream_t stream) {
  (void)in_sizes; (void)n_in; (void)out_size; (void)ws_size;
  const float* x      = (const float*)d_in[0];
  const float* log_dt = (const float*)d_in[1];
  const float* Alog   = (const float*)d_in[2];
  const float* Aim    = (const float*)d_in[3];
  const float* Cre    = (const float*)d_in[4];
  const float* Cim    = (const float*)d_in[5];
  const float* Dv     = (const float*)d_in[6];
  const float* Wout   = (const float*)d_in[7];
  const float* bout   = (const float*)d_in[8];
  const float* lns    = (const float*)d_in[9];
  const float* lnb    = (const float*)d_in[10];

  float* hb = (float*)d_out;
  float* ws = (float*)d_ws;
  float* zn  = ws;                  // (B,L,H) f32
  float* ybc = ws + SZ;             // corr    (B,L,H) f32
  float* S   = ws + 2 * SZ;         // (B,NC,H,N) cplx f32  (= SZ floats)
  __hip_bfloat16* ybb = (__hip_bfloat16*)(ws + 3 * SZ);       // (B,L,H) bf16
  __hip_bfloat16* Wb  = (__hip_bfloat16*)(ws + 3 * SZ + SZ/2); // 4x512x256 bf16
  float* wv  = ws + 3 * SZ + SZ/2 + (NL * 2 * Hq * Hq) / 2;
  float* wLc = wv  + 2 * Hq * Nst;
  float* w65 = wLc + 2 * Hq * Nst;
  float* Cd  = w65 + 2 * Hq * Nst;
  float* Kt  = Cd  + 2 * Hq * Nst;  // (H,128)

  hipMemcpyAsync(hb, x, SZ * sizeof(float), hipMemcpyDeviceToDevice, stream);
  cvtw_k<<<(NL * 2 * Hq * Hq) / 256, 256, 0, stream>>>(Wout, Wb, NL * 2 * Hq * Hq);

  for (int i = 0; i < NL; ++i) {
    paramA_k<<<(Hq * Nst) / 256, 256, 0, stream>>>(
        log_dt + i * Hq, Alog + (size_t)i * Hq * Nst, Aim + (size_t)i * Hq * Nst,
        Cre + (size_t)i * Hq * Nst, Cim + (size_t)i * Hq * Nst, wv, wLc, w65, Cd);
    paramB_k<<<Hq, 64, 0, stream>>>(wv, Cd, Kt);
    ln_k<<<(Bq * Lq) / 4, 256, 0, stream>>>(hb, lns + i * Hq, lnb + i * Hq, zn);
    pass1_k<<<Bq * NC * 2, 1024, 0, stream>>>(zn, wv, S);
    scan_k<<<(Bq * Hq * Nst) / 256, 256, 0, stream>>>(S, wLc);
    pass3a_k<<<Bq * NC * 2, 256, 0, stream>>>(S, wv, w65, Cd, ybc);
    pass3b_k<<<Bq * NC * 4, 512, 0, stream>>>(zn, Kt, Dv + i * Hq, ybc, ybb);
    gemm_k<<<dim3((Bq * Lq) / 128, 4), 256, 0, stream>>>(
        ybb, Wb + (size_t)i * 2 * Hq * Hq, bout + (size_t)i * 2 * Hq, hb);
  }
}

// Round 6
// 601.618 us; speedup vs baseline: 3.9707x; 2.6843x over previous
//
#include <hip/hip_runtime.h>
#include <hip/hip_bf16.h>
#include <math.h>

#define Bq 16
#define Lq 2048
#define Hq 256
#define Nst 64
#define LC 128
#define NC 16
#define NL 4
#define BC 256   // Bq*NC
#define GK 256
#define SZ ((size_t)Bq * Lq * Hq)   // 8388608

typedef __attribute__((ext_vector_type(8))) short short8;
typedef __attribute__((ext_vector_type(4))) float f32x4;
typedef unsigned short u16;
typedef unsigned int u32;

__device__ __forceinline__ u16 f2b(float x) {
  __hip_bfloat16 b = __float2bfloat16(x);
  u16 u; __builtin_memcpy(&u, &b, 2); return u;
}
__device__ __forceinline__ float b2f(u16 u) {
  u32 t = ((u32)u) << 16; float f; __builtin_memcpy(&f, &t, 4); return f;
}
__device__ __forceinline__ void gload16(const void* g, void* l) {
  __builtin_amdgcn_global_load_lds(
      (const __attribute__((address_space(1))) void*)g,
      (__attribute__((address_space(3))) void*)l, 16, 0, 0);
}

// ---------------- paramA: w, w^128, dtA, Cd per (h,n) ----------------
__global__ __launch_bounds__(256) void paramA_k(
    const float* __restrict__ log_dt, const float* __restrict__ Alog,
    const float* __restrict__ Aim, const float* __restrict__ Cre,
    const float* __restrict__ Cim,
    float* __restrict__ wv, float* __restrict__ wLc,
    float* __restrict__ dA, float* __restrict__ Cd) {
  int i = blockIdx.x * blockDim.x + threadIdx.x;   // h*Nst + n
  if (i >= Hq * Nst) return;
  int h = i >> 6;
  float dt = expf(log_dt[h]);
  float ar = -expf(Alog[i]);
  float ai = Aim[i];
  float dr = ar * dt, di = ai * dt;
  dA[2*i] = dr; dA[2*i+1] = di;
  float er = expf(dr); float sn, cs; sincosf(di, &sn, &cs);
  float wr = er * cs, wi = er * sn;
  wv[2*i] = wr; wv[2*i+1] = wi;
  float e2 = expf(dr * (float)LC); float sn2, cs2; sincosf(di * (float)LC, &sn2, &cs2);
  wLc[2*i] = e2 * cs2; wLc[2*i+1] = e2 * sn2;
  float nr = wr - 1.f, ni = wi;
  float d2 = ar*ar + ai*ai;
  float qr = (nr*ar + ni*ai) / d2;
  float qi = (ni*ar - nr*ai) / d2;
  float cr = Cre[i], ci = Cim[i];
  Cd[2*i]   = cr*qr - ci*qi;
  Cd[2*i+1] = cr*qi + ci*qr;
}

// Kt[h][m] = 2*Re(sum_n Cd w^m)  (+ D[h] folded into tap 0)
__global__ __launch_bounds__(64) void paramB_k(
    const float* __restrict__ wv, const float* __restrict__ Cd,
    const float* __restrict__ Dv, float* __restrict__ Kt) {
  int h = blockIdx.x, n = threadIdx.x;
  int i = h * Nst + n;
  float wr = wv[2*i], wi = wv[2*i+1];
  float cr = Cd[2*i], ci = Cd[2*i+1];
  float pr = 1.f, pi = 0.f;
  for (int m = 0; m < LC; ++m) {
    float v = 2.f * (cr*pr - ci*pi);
    for (int off = 32; off; off >>= 1) v += __shfl_down(v, off);
    if (n == 0) Kt[h * LC + m] = v + (m == 0 ? Dv[h] : 0.f);
    float t = pr*wr - pi*wi;
    pi = fmaf(pr, wi, pi*wr);
    pr = t;
  }
}

// ---------------- paramM: build Vb[h][rr][j], TRb[h][t][k] bf16 ----------------
__global__ __launch_bounds__(256) void paramM_k(
    const float* __restrict__ dA, const float* __restrict__ Cd,
    const float* __restrict__ Kt, u16* __restrict__ Vb, u16* __restrict__ TRb) {
  int h = blockIdx.x;
  int wid = threadIdx.x >> 6, lane = threadIdx.x & 63;
  __shared__ float kts[LC];
  if (threadIdx.x < LC) kts[threadIdx.x] = Kt[h * LC + threadIdx.x];
  __syncthreads();
  if (wid < 2) {
    // V rows rr: V[rr][j] = (rr even? Re : Im)(w_n^(127-j)), n = rr>>1
    for (int ro = 0; ro < 64; ++ro) {
      int rr = wid * 64 + ro;
      int n = rr >> 1, im = rr & 1;
      float dr = dA[(h*Nst+n)*2], di = dA[(h*Nst+n)*2+1];
      #pragma unroll
      for (int half = 0; half < 2; ++half) {
        int j = lane + half * 64;
        float p = (float)(127 - j);
        float e = expf(dr * p); float sn, cs; sincosf(di * p, &sn, &cs);
        Vb[((size_t)h * 128 + rr) * 128 + j] = f2b(im ? e * sn : e * cs);
      }
    }
  } else {
    // TR rows t: k<128 -> Toeplitz kt[t-j]; k>=128 -> readout R
    for (int to = 0; to < 64; ++to) {
      int t = (wid - 2) * 64 + to;
      #pragma unroll
      for (int half = 0; half < 2; ++half) {
        int j = lane + half * 64;
        float v = (j <= t) ? kts[t - j] : 0.f;
        TRb[((size_t)h * 128 + t) * 256 + j] = f2b(v);
      }
      #pragma unroll
      for (int half = 0; half < 2; ++half) {
        int rr = lane + half * 64;
        int n = rr >> 1, im = rr & 1;
        float dr = dA[(h*Nst+n)*2], di = dA[(h*Nst+n)*2+1];
        float cr = Cd[(h*Nst+n)*2], ci = Cd[(h*Nst+n)*2+1];
        float p = (float)(t + 1);
        float e = expf(dr * p); float sn, cs; sincosf(di * p, &sn, &cs);
        float wpr = e * cs, wpi = e * sn;
        float qr = cr*wpr - ci*wpi, qi = cr*wpi + ci*wpr;
        TRb[((size_t)h * 128 + t) * 256 + 128 + rr] = f2b(im ? -2.f*qi : 2.f*qr);
      }
    }
  }
}

// ---------------- W -> bf16 ----------------
__global__ __launch_bounds__(256) void cvtw_k(
    const float* __restrict__ w, __hip_bfloat16* __restrict__ wb, int n) {
  int i = blockIdx.x * 256 + threadIdx.x;
  if (i < n) wb[i] = __float2bfloat16(w[i]);
}

// ---------------- layernorm -> bf16 ----------------
__global__ __launch_bounds__(256) void ln_k(
    const float* __restrict__ hb, const float* __restrict__ sc,
    const float* __restrict__ bi, u16* __restrict__ znb) {
  int row = blockIdx.x * 4 + (threadIdx.x >> 6);
  int lane = threadIdx.x & 63;
  const float4 v = ((const float4*)(hb + (size_t)row * Hq))[lane];
  float s  = v.x + v.y + v.z + v.w;
  float s2 = v.x*v.x + v.y*v.y + v.z*v.z + v.w*v.w;
  for (int off = 32; off; off >>= 1) { s += __shfl_down(s, off); s2 += __shfl_down(s2, off); }
  s = __shfl(s, 0); s2 = __shfl(s2, 0);
  float mu = s * (1.f / Hq);
  float var = s2 * (1.f / Hq) - mu * mu;
  float r = rsqrtf(var + 1e-5f);
  float4 scv = ((const float4*)sc)[lane];
  float4 biv = ((const float4*)bi)[lane];
  ushort4 ov;
  ov.x = f2b((v.x - mu) * r * scv.x + biv.x);
  ov.y = f2b((v.y - mu) * r * scv.y + biv.y);
  ov.z = f2b((v.z - mu) * r * scv.z + biv.z);
  ov.w = f2b((v.w - mu) * r * scv.w + biv.w);
  ((ushort4*)(znb + (size_t)row * Hq))[lane] = ov;
}

// ---------------- trA: znb (bl, h) bf16 -> zt (h, bc, j) bf16 ----------------
__global__ __launch_bounds__(256) void trA_k(
    const u16* __restrict__ znb, u16* __restrict__ zt) {
  int bc = blockIdx.x;
  int h0 = blockIdx.y * 64;
  __shared__ float Lt[128][65];
  const u16* src = znb + (size_t)bc * LC * Hq + h0;
  for (int it = 0; it < 16; ++it) {
    int idx = it * 256 + threadIdx.x;
    int j = idx >> 5, hl = idx & 31;
    u32 v = *(const u32*)(src + (size_t)j * Hq + 2 * hl);
    Lt[j][2*hl]   = b2f((u16)(v & 0xffff));
    Lt[j][2*hl+1] = b2f((u16)(v >> 16));
  }
  __syncthreads();
  for (int it = 0; it < 16; ++it) {
    int idx = it * 256 + threadIdx.x;
    int hc = idx >> 6, jl = idx & 63;
    u32 lo = f2b(Lt[2*jl][hc]);
    u32 hi = f2b(Lt[2*jl+1][hc]);
    ((u32*)zt)[((size_t)(h0 + hc) * BC + bc) * 64 + jl] = lo | (hi << 16);
  }
}

// ---------------- pass1m: S[bc,rr] = U_h . V_h  (MFMA) ----------------
__global__ __launch_bounds__(512) void pass1m_k(
    const u16* __restrict__ zt, const u16* __restrict__ Vb,
    float* __restrict__ Sf) {
  int h = blockIdx.y;
  int m0 = blockIdx.x * 128;
  __shared__ u16 As[128 * 64], Bs[128 * 64];
  int tid = threadIdx.x;
  int wid = tid >> 6, lane = tid & 63;
  int cl = lane & 15, kq = lane >> 4;
  int wm = wid & 1, wn = wid >> 1;
  f32x4 acc[4][2] = {};
  const u16* Ab = zt + ((size_t)h * BC + m0) * 128;
  const u16* Bb = Vb + (size_t)h * 128 * 128;
  for (int step = 0; step < 2; ++step) {
    int col0 = step * 64;
    #pragma unroll
    for (int q = 0; q < 2; ++q) {
      int idx = q * 512 + tid;
      int r = idx >> 3, ch = idx & 7;
      gload16(Ab + (size_t)r * 128 + col0 + ((ch ^ (r & 7)) << 3),
              (char*)As + (size_t)(q * 512 + (tid & ~63)) * 16);
      gload16(Bb + (size_t)r * 128 + col0 + ((ch ^ (r & 7)) << 3),
              (char*)Bs + (size_t)(q * 512 + (tid & ~63)) * 16);
    }
    __syncthreads();
    #pragma unroll
    for (int kk = 0; kk < 2; ++kk) {
      short8 a[4], bf[2];
      #pragma unroll
      for (int mi = 0; mi < 4; ++mi) {
        int m = wm * 64 + mi * 16 + cl;
        int ch = (kk * 4 + kq) ^ (m & 7);
        a[mi] = *(const short8*)(As + m * 64 + ch * 8);
      }
      #pragma unroll
      for (int ni = 0; ni < 2; ++ni) {
        int n = wn * 32 + ni * 16 + cl;
        int ch = (kk * 4 + kq) ^ (n & 7);
        bf[ni] = *(const short8*)(Bs + n * 64 + ch * 8);
      }
      #pragma unroll
      for (int mi = 0; mi < 4; ++mi)
        #pragma unroll
        for (int ni = 0; ni < 2; ++ni)
          acc[mi][ni] = __builtin_amdgcn_mfma_f32_16x16x32_bf16(
              a[mi], bf[ni], acc[mi][ni], 0, 0, 0);
    }
    __syncthreads();
  }
  #pragma unroll
  for (int mi = 0; mi < 4; ++mi)
    #pragma unroll
    for (int ni = 0; ni < 2; ++ni) {
      int colv = wn * 32 + ni * 16 + cl;
      #pragma unroll
      for (int r = 0; r < 4; ++r) {
        int row = m0 + wm * 64 + mi * 16 + kq * 4 + r;
        Sf[((size_t)h * BC + row) * 128 + colv] = acc[mi][ni][r];
      }
    }
}

// ---------------- scan over chunks; emit bf16 prev-state slots ----------------
__global__ __launch_bounds__(256) void scan_k(
    const float* __restrict__ Sf, const float* __restrict__ wLc,
    u16* __restrict__ Sb) {
  int i = blockIdx.x * 256 + threadIdx.x;   // (b, h, n)
  int n = i & 63;
  int h = (i >> 6) & 255;
  int b = i >> 14;
  int hn = h * Nst + n;
  float wr = wLc[2*hn], wi = wLc[2*hn+1];
  float sr = 0.f, si = 0.f;
  for (int c = 0; c < NC; ++c) {
    size_t o = ((size_t)h * BC + b * NC + c) * 128 + 2 * n;
    ((u32*)Sb)[o >> 1] = (u32)f2b(sr) | ((u32)f2b(si) << 16);  // prev state
    float2 a = *(const float2*)(Sf + o);
    float nr2 = fmaf(wr, sr, fmaf(-wi, si, a.x));
    float ni2 = fmaf(wr, si, fmaf( wi, sr, a.y));
    sr = nr2; si = ni2;
  }
}

// ---------------- conv: Y = U.T + Sprev.R, +GELU (MFMA) ----------------
__global__ __launch_bounds__(512) void conv_k(
    const u16* __restrict__ zt, const u16* __restrict__ Sb,
    const u16* __restrict__ TRb, u16* __restrict__ ytb) {
  int h = blockIdx.y;
  int m0 = blockIdx.x * 128;
  __shared__ u16 As[128 * 64], Bs[128 * 64];
  int tid = threadIdx.x;
  int wid = tid >> 6, lane = tid & 63;
  int cl = lane & 15, kq = lane >> 4;
  int wm = wid & 1, wn = wid >> 1;
  f32x4 acc[4][2] = {};
  const u16* Bb = TRb + (size_t)h * 128 * 256;
  for (int step = 0; step < 4; ++step) {
    const u16* Ab = (step < 2 ? zt : Sb) + ((size_t)h * BC + m0) * 128;
    int col0 = (step & 1) * 64;
    #pragma unroll
    for (int q = 0; q < 2; ++q) {
      int idx = q * 512 + tid;
      int r = idx >> 3, ch = idx & 7;
      gload16(Ab + (size_t)r * 128 + col0 + ((ch ^ (r & 7)) << 3),
              (char*)As + (size_t)(q * 512 + (tid & ~63)) * 16);
      gload16(Bb + (size_t)r * 256 + step * 64 + ((ch ^ (r & 7)) << 3),
              (char*)Bs + (size_t)(q * 512 + (tid & ~63)) * 16);
    }
    __syncthreads();
    #pragma unroll
    for (int kk = 0; kk < 2; ++kk) {
      short8 a[4], bf[2];
      #pragma unroll
      for (int mi = 0; mi < 4; ++mi) {
        int m = wm * 64 + mi * 16 + cl;
        int ch = (kk * 4 + kq) ^ (m & 7);
        a[mi] = *(const short8*)(As + m * 64 + ch * 8);
      }
      #pragma unroll
      for (int ni = 0; ni < 2; ++ni) {
        int n = wn * 32 + ni * 16 + cl;
        int ch = (kk * 4 + kq) ^ (n & 7);
        bf[ni] = *(const short8*)(Bs + n * 64 + ch * 8);
      }
      #pragma unroll
      for (int mi = 0; mi < 4; ++mi)
        #pragma unroll
        for (int ni = 0; ni < 2; ++ni)
          acc[mi][ni] = __builtin_amdgcn_mfma_f32_16x16x32_bf16(
              a[mi], bf[ni], acc[mi][ni], 0, 0, 0);
    }
    __syncthreads();
  }
  #pragma unroll
  for (int mi = 0; mi < 4; ++mi)
    #pragma unroll
    for (int ni = 0; ni < 2; ++ni) {
      int t = wn * 32 + ni * 16 + cl;
      #pragma unroll
      for (int r = 0; r < 4; ++r) {
        int row = m0 + wm * 64 + mi * 16 + kq * 4 + r;
        float x = acc[mi][ni][r];
        float inner = 0.7978845608028654f * fmaf(0.044715f, x*x*x, x);
        float g = 0.5f * x * (1.f + tanhf(inner));
        ytb[((size_t)h * BC + row) * LC + t] = f2b(g);
      }
    }
}

// ---------------- trB: ytb (h, bc, t) -> ybb (bl, h) bf16 ----------------
__global__ __launch_bounds__(256) void trB_k(
    const u16* __restrict__ ytb, u16* __restrict__ ybb) {
  int bc = blockIdx.x;
  int h0 = blockIdx.y * 64;
  __shared__ float Lt[128][65];
  const u16* src = ytb + ((size_t)h0 * BC + bc) * LC;
  for (int it = 0; it < 16; ++it) {
    int idx = it * 256 + threadIdx.x;
    int hh = idx >> 6, tl = idx & 63;
    u32 v = *(const u32*)(src + (size_t)hh * BC * LC + 2 * tl);
    Lt[2*tl][hh]   = b2f((u16)(v & 0xffff));
    Lt[2*tl+1][hh] = b2f((u16)(v >> 16));
  }
  __syncthreads();
  for (int it = 0; it < 16; ++it) {
    int idx = it * 256 + threadIdx.x;
    int t = idx >> 5, hl = idx & 31;
    u32 lo = f2b(Lt[t][2*hl]);
    u32 hi = f2b(Lt[t][2*hl+1]);
    ((u32*)ybb)[((size_t)bc * LC + t) * (Hq / 2) + h0 / 2 + hl] = lo | (hi << 16);
  }
}

// ---------------- bf16 MFMA GEMM + bias + GLU + residual ----------------
__global__ __launch_bounds__(256) void gemm_k(
    const __hip_bfloat16* __restrict__ ybb, const __hip_bfloat16* __restrict__ Wb,
    const float* __restrict__ bout, float* __restrict__ hb) {
  __shared__ __hip_bfloat16 As[128 * 64];
  __shared__ __hip_bfloat16 Bs[128 * 64];
  int tid = threadIdx.x;
  int m0 = blockIdx.x * 128;
  int ot = blockIdx.y;
  int wid = tid >> 6, lane = tid & 63;
  int cl = lane & 15, kq = lane >> 4;
  f32x4 acc[2][8] = {};
  for (int kt = 0; kt < GK / 64; ++kt) {
    int k0 = kt * 64;
    #pragma unroll
    for (int q = 0; q < 4; ++q) {
      int idx = q * 256 + tid;
      int r = idx >> 3, ch = idx & 7;
      const __hip_bfloat16* sA =
          ybb + (size_t)(m0 + r) * GK + k0 + ((ch ^ (r & 7)) << 3);
      gload16(sA, (char*)As + (size_t)(q * 256 + (tid & ~63)) * 16);
      int wrow = ot * 64 + r + ((r >= 64) ? 192 : 0);
      const __hip_bfloat16* sB =
          Wb + (size_t)wrow * GK + k0 + ((ch ^ (r & 7)) << 3);
      gload16(sB, (char*)Bs + (size_t)(q * 256 + (tid & ~63)) * 16);
    }
    __syncthreads();
    #pragma unroll
    for (int kk = 0; kk < 2; ++kk) {
      short8 a[2], bfr[8];
      #pragma unroll
      for (int mi = 0; mi < 2; ++mi) {
        int m = wid * 32 + mi * 16 + cl;
        int ch = (kk * 4 + kq) ^ (m & 7);
        a[mi] = *(const short8*)(As + m * 64 + ch * 8);
      }
      #pragma unroll
      for (int ni = 0; ni < 8; ++ni) {
        int n = ni * 16 + cl;
        int ch = (kk * 4 + kq) ^ (n & 7);
        bfr[ni] = *(const short8*)(Bs + n * 64 + ch * 8);
      }
      #pragma unroll
      for (int mi = 0; mi < 2; ++mi)
        #pragma unroll
        for (int ni = 0; ni < 8; ++ni)
          acc[mi][ni] = __builtin_amdgcn_mfma_f32_16x16x32_bf16(
              a[mi], bfr[ni], acc[mi][ni], 0, 0, 0);
    }
    __syncthreads();
  }
  #pragma unroll
  for (int mi = 0; mi < 2; ++mi) {
    #pragma unroll
    for (int ni = 0; ni < 4; ++ni) {
      int o1 = ot * 64 + ni * 16 + cl;
      float b1 = bout[o1], b2 = bout[o1 + 256];
      #pragma unroll
      for (int r = 0; r < 4; ++r) {
        int row = m0 + wid * 32 + mi * 16 + kq * 4 + r;
        float z1 = acc[mi][ni][r] + b1;
        float z2 = acc[mi][ni + 4][r] + b2;
        float g = z1 / (1.f + expf(-z2));
        hb[(size_t)row * Hq + o1] += g;
      }
    }
  }
}

extern "C" void kernel_launch(void* const* d_in, const int* in_sizes, int n_in,
                              void* d_out, int out_size, void* d_ws, size_t ws_size,
                              hipStream_t stream) {
  (void)in_sizes; (void)n_in; (void)out_size; (void)ws_size;
  const float* x      = (const float*)d_in[0];
  const float* log_dt = (const float*)d_in[1];
  const float* Alog   = (const float*)d_in[2];
  const float* Aim    = (const float*)d_in[3];
  const float* Cre    = (const float*)d_in[4];
  const float* Cim    = (const float*)d_in[5];
  const float* Dv     = (const float*)d_in[6];
  const float* Wout   = (const float*)d_in[7];
  const float* bout   = (const float*)d_in[8];
  const float* lns    = (const float*)d_in[9];
  const float* lnb    = (const float*)d_in[10];

  float* hb = (float*)d_out;
  float* ws = (float*)d_ws;
  // workspace (floats). Aliases (safe by liveness):
  //   znb (ln out, dead after trA) ∪ ybb (written trB, read gemm)
  //   Sf (dead after scan) ∪ ytb (written conv, read trB)
  u16* znb = (u16*)ws;                         // SZ ushort
  u16* ybb = znb;                              // alias
  u16* zt  = (u16*)(ws + SZ/2);                // SZ ushort
  float* Sf = ws + SZ;                         // SZ floats
  u16* ytb = (u16*)Sf;                         // alias
  float* p  = Sf + SZ;
  u16* Sb  = (u16*)p; p += SZ/2;               // SZ ushort
  u16* Vb  = (u16*)p; p += SZ/4;               // H*128*128 ushort
  u16* TRb = (u16*)p; p += SZ/2;               // H*128*256 ushort
  u16* Wb  = (u16*)p; p += (NL*2*Hq*Hq)/2;     // bf16 weights
  float* wv  = p;  p += 2*Hq*Nst;
  float* wLc = p;  p += 2*Hq*Nst;
  float* dA  = p;  p += 2*Hq*Nst;
  float* Cd  = p;  p += 2*Hq*Nst;
  float* Kt  = p;  p += Hq*LC;

  hipMemcpyAsync(hb, x, SZ * sizeof(float), hipMemcpyDeviceToDevice, stream);
  cvtw_k<<<(NL*2*Hq*Hq)/256, 256, 0, stream>>>(Wout, (__hip_bfloat16*)Wb, NL*2*Hq*Hq);

  for (int i = 0; i < NL; ++i) {
    paramA_k<<<(Hq*Nst)/256, 256, 0, stream>>>(
        log_dt + i*Hq, Alog + (size_t)i*Hq*Nst, Aim + (size_t)i*Hq*Nst,
        Cre + (size_t)i*Hq*Nst, Cim + (size_t)i*Hq*Nst, wv, wLc, dA, Cd);
    paramB_k<<<Hq, 64, 0, stream>>>(wv, Cd, Dv + i*Hq, Kt);
    paramM_k<<<Hq, 256, 0, stream>>>(dA, Cd, Kt, Vb, TRb);
    ln_k<<<(Bq*Lq)/4, 256, 0, stream>>>(hb, lns + i*Hq, lnb + i*Hq, znb);
    trA_k<<<dim3(BC, 4), 256, 0, stream>>>(znb, zt);
    pass1m_k<<<dim3(2, Hq), 512, 0, stream>>>(zt, Vb, Sf);
    scan_k<<<(Bq*Hq*Nst)/256, 256, 0, stream>>>(Sf, wLc, Sb);
    conv_k<<<dim3(2, Hq), 512, 0, stream>>>(zt, Sb, TRb, ytb);
    trB_k<<<dim3(BC, 4), 256, 0, stream>>>(ytb, ybb);
    gemm_k<<<dim3((Bq*Lq)/128, 4), 256, 0, stream>>>(
        (const __hip_bfloat16*)ybb,
        (const __hip_bfloat16*)(Wb + (size_t)i * 2 * Hq * Hq),   // <-- the fix
        bout + (size_t)i*2*Hq, hb);
  }
}

// Round 7
// 561.596 us; speedup vs baseline: 4.2537x; 1.0713x over previous
//
#include <hip/hip_runtime.h>
#include <hip/hip_bf16.h>
#include <math.h>

#define Bq 16
#define Lq 2048
#define Hq 256
#define Nst 64
#define LC 128
#define NC 16
#define NL 4
#define BC 256   // Bq*NC
#define GK 256
#define SZ ((size_t)Bq * Lq * Hq)   // 8388608

typedef __attribute__((ext_vector_type(8))) short short8;
typedef __attribute__((ext_vector_type(4))) float f32x4;
typedef unsigned short u16;
typedef unsigned int u32;

__device__ __forceinline__ u16 f2b(float x) {
  __hip_bfloat16 b = __float2bfloat16(x);
  u16 u; __builtin_memcpy(&u, &b, 2); return u;
}
__device__ __forceinline__ float b2f(u16 u) {
  u32 t = ((u32)u) << 16; float f; __builtin_memcpy(&f, &t, 4); return f;
}
__device__ __forceinline__ void gload16(const void* g, void* l) {
  __builtin_amdgcn_global_load_lds(
      (const __attribute__((address_space(1))) void*)g,
      (__attribute__((address_space(3))) void*)l, 16, 0, 0);
}

// ---------------- paramA: w, w^128, dtA, Cd per (h,n) ----------------
__global__ __launch_bounds__(256) void paramA_k(
    const float* __restrict__ log_dt, const float* __restrict__ Alog,
    const float* __restrict__ Aim, const float* __restrict__ Cre,
    const float* __restrict__ Cim,
    float* __restrict__ wv, float* __restrict__ wLc,
    float* __restrict__ dA, float* __restrict__ Cd) {
  int i = blockIdx.x * blockDim.x + threadIdx.x;   // h*Nst + n
  if (i >= Hq * Nst) return;
  int h = i >> 6;
  float dt = expf(log_dt[h]);
  float ar = -expf(Alog[i]);
  float ai = Aim[i];
  float dr = ar * dt, di = ai * dt;
  dA[2*i] = dr; dA[2*i+1] = di;
  float er = expf(dr); float sn, cs; sincosf(di, &sn, &cs);
  float wr = er * cs, wi = er * sn;
  wv[2*i] = wr; wv[2*i+1] = wi;
  float e2 = expf(dr * (float)LC); float sn2, cs2; sincosf(di * (float)LC, &sn2, &cs2);
  wLc[2*i] = e2 * cs2; wLc[2*i+1] = e2 * sn2;
  float nr = wr - 1.f, ni = wi;
  float d2 = ar*ar + ai*ai;
  float qr = (nr*ar + ni*ai) / d2;
  float qi = (ni*ar - nr*ai) / d2;
  float cr = Cre[i], ci = Cim[i];
  Cd[2*i]   = cr*qr - ci*qi;
  Cd[2*i+1] = cr*qi + ci*qr;
}

// Kt[h][m] = 2*Re(sum_n Cd w^m)  (+ D[h] folded into tap 0)
__global__ __launch_bounds__(64) void paramB_k(
    const float* __restrict__ wv, const float* __restrict__ Cd,
    const float* __restrict__ Dv, float* __restrict__ Kt) {
  int h = blockIdx.x, n = threadIdx.x;
  int i = h * Nst + n;
  float wr = wv[2*i], wi = wv[2*i+1];
  float cr = Cd[2*i], ci = Cd[2*i+1];
  float pr = 1.f, pi = 0.f;
  for (int m = 0; m < LC; ++m) {
    float v = 2.f * (cr*pr - ci*pi);
    for (int off = 32; off; off >>= 1) v += __shfl_down(v, off);
    if (n == 0) Kt[h * LC + m] = v + (m == 0 ? Dv[h] : 0.f);
    float t = pr*wr - pi*wi;
    pi = fmaf(pr, wi, pi*wr);
    pr = t;
  }
}

// ---------------- paramM: build Vb[h][rr][j], TRb[h][t][k] bf16 ----------------
__global__ __launch_bounds__(256) void paramM_k(
    const float* __restrict__ dA, const float* __restrict__ Cd,
    const float* __restrict__ Kt, u16* __restrict__ Vb, u16* __restrict__ TRb) {
  int h = blockIdx.x;
  int wid = threadIdx.x >> 6, lane = threadIdx.x & 63;
  __shared__ float kts[LC];
  if (threadIdx.x < LC) kts[threadIdx.x] = Kt[h * LC + threadIdx.x];
  __syncthreads();
  if (wid < 2) {
    for (int ro = 0; ro < 64; ++ro) {
      int rr = wid * 64 + ro;
      int n = rr >> 1, im = rr & 1;
      float dr = dA[(h*Nst+n)*2], di = dA[(h*Nst+n)*2+1];
      #pragma unroll
      for (int half = 0; half < 2; ++half) {
        int j = lane + half * 64;
        float p = (float)(127 - j);
        float e = expf(dr * p); float sn, cs; sincosf(di * p, &sn, &cs);
        Vb[((size_t)h * 128 + rr) * 128 + j] = f2b(im ? e * sn : e * cs);
      }
    }
  } else {
    for (int to = 0; to < 64; ++to) {
      int t = (wid - 2) * 64 + to;
      #pragma unroll
      for (int half = 0; half < 2; ++half) {
        int j = lane + half * 64;
        float v = (j <= t) ? kts[t - j] : 0.f;
        TRb[((size_t)h * 128 + t) * 256 + j] = f2b(v);
      }
      #pragma unroll
      for (int half = 0; half < 2; ++half) {
        int rr = lane + half * 64;
        int n = rr >> 1, im = rr & 1;
        float dr = dA[(h*Nst+n)*2], di = dA[(h*Nst+n)*2+1];
        float cr = Cd[(h*Nst+n)*2], ci = Cd[(h*Nst+n)*2+1];
        float p = (float)(t + 1);
        float e = expf(dr * p); float sn, cs; sincosf(di * p, &sn, &cs);
        float wpr = e * cs, wpi = e * sn;
        float qr = cr*wpr - ci*wpi, qi = cr*wpi + ci*wpr;
        TRb[((size_t)h * 128 + t) * 256 + 128 + rr] = f2b(im ? -2.f*qi : 2.f*qr);
      }
    }
  }
}

// ---------------- W -> bf16 ----------------
__global__ __launch_bounds__(256) void cvtw_k(
    const float* __restrict__ w, __hip_bfloat16* __restrict__ wb, int n) {
  int i = blockIdx.x * 256 + threadIdx.x;
  if (i < n) wb[i] = __float2bfloat16(w[i]);
}

// ---------------- layernorm -> bf16 ----------------
__global__ __launch_bounds__(256) void ln_k(
    const float* __restrict__ hb, const float* __restrict__ sc,
    const float* __restrict__ bi, u16* __restrict__ znb) {
  int row = blockIdx.x * 4 + (threadIdx.x >> 6);
  int lane = threadIdx.x & 63;
  const float4 v = ((const float4*)(hb + (size_t)row * Hq))[lane];
  float s  = v.x + v.y + v.z + v.w;
  float s2 = v.x*v.x + v.y*v.y + v.z*v.z + v.w*v.w;
  for (int off = 32; off; off >>= 1) { s += __shfl_down(s, off); s2 += __shfl_down(s2, off); }
  s = __shfl(s, 0); s2 = __shfl(s2, 0);
  float mu = s * (1.f / Hq);
  float var = s2 * (1.f / Hq) - mu * mu;
  float r = rsqrtf(var + 1e-5f);
  float4 scv = ((const float4*)sc)[lane];
  float4 biv = ((const float4*)bi)[lane];
  ushort4 ov;
  ov.x = f2b((v.x - mu) * r * scv.x + biv.x);
  ov.y = f2b((v.y - mu) * r * scv.y + biv.y);
  ov.z = f2b((v.z - mu) * r * scv.z + biv.z);
  ov.w = f2b((v.w - mu) * r * scv.w + biv.w);
  ((ushort4*)(znb + (size_t)row * Hq))[lane] = ov;
}

// ---------------- trA: znb (bl, h) bf16 -> zt (h, bc, j) bf16 ----------------
__global__ __launch_bounds__(256) void trA_k(
    const u16* __restrict__ znb, u16* __restrict__ zt) {
  int bc = blockIdx.x;
  int h0 = blockIdx.y * 64;
  __shared__ float Lt[128][65];
  const u16* src = znb + (size_t)bc * LC * Hq + h0;
  for (int it = 0; it < 16; ++it) {
    int idx = it * 256 + threadIdx.x;
    int j = idx >> 5, hl = idx & 31;
    u32 v = *(const u32*)(src + (size_t)j * Hq + 2 * hl);
    Lt[j][2*hl]   = b2f((u16)(v & 0xffff));
    Lt[j][2*hl+1] = b2f((u16)(v >> 16));
  }
  __syncthreads();
  for (int it = 0; it < 16; ++it) {
    int idx = it * 256 + threadIdx.x;
    int hc = idx >> 6, jl = idx & 63;
    u32 lo = f2b(Lt[2*jl][hc]);
    u32 hi = f2b(Lt[2*jl+1][hc]);
    ((u32*)zt)[((size_t)(h0 + hc) * BC + bc) * 64 + jl] = lo | (hi << 16);
  }
}

// ---------------- s4core: S_local MFMA + in-reg chunk scan + conv MFMA + GELU ----
// Per block (m0, h): rows bc = m0..m0+127 (8 b-groups x 16 chunks, scan is
// block-local). Phase 1: S_local = U.V (K=128). In-register f32 scan over c
// (C-layout: b=(row>>4) fixed per (wm,mi); c=kq*4+r; re/im split across cl&1
// lanes -> shfl_xor(1) partner + shfl carry broadcast; same math/order as the
// verified scan_k). Prev-states -> bf16 -> As LDS region (zt dead). Phase 2:
// Y = U.T + Sprev.R, GELU, write ytb.
__global__ __launch_bounds__(512) void s4core_k(
    const u16* __restrict__ zt, const u16* __restrict__ Vb,
    const u16* __restrict__ TRb, const float* __restrict__ wLc,
    u16* __restrict__ ytb) {
  int h = blockIdx.y;
  int m0 = blockIdx.x * 128;
  __shared__ u16 As[2][128 * 64];   // zt K-halves; later overwritten with Sprev
  __shared__ u16 Bs[128 * 64];
  int tid = threadIdx.x;
  int wid = tid >> 6, lane = tid & 63;
  int cl = lane & 15, kq = lane >> 4;
  int wm = wid & 1, wn = wid >> 1;

  const u16* Ab  = zt  + ((size_t)h * BC + m0) * 128;
  const u16* Vbb = Vb  + (size_t)h * 128 * 128;
  const u16* Tbb = TRb + (size_t)h * 128 * 256;

  // stage both zt K-halves once
  #pragma unroll
  for (int half = 0; half < 2; ++half)
    #pragma unroll
    for (int q = 0; q < 2; ++q) {
      int idx = q * 512 + tid;
      int r = idx >> 3, ch = idx & 7;
      gload16(Ab + (size_t)r * 128 + half * 64 + ((ch ^ (r & 7)) << 3),
              (char*)As[half] + (size_t)(q * 512 + (tid & ~63)) * 16);
    }

  auto stageB = [&](const u16* base, int stride, int col0) {
    #pragma unroll
    for (int q = 0; q < 2; ++q) {
      int idx = q * 512 + tid;
      int r = idx >> 3, ch = idx & 7;
      gload16(base + (size_t)r * stride + col0 + ((ch ^ (r & 7)) << 3),
              (char*)Bs + (size_t)(q * 512 + (tid & ~63)) * 16);
    }
  };

  f32x4 accS[4][2] = {};
  f32x4 accY[4][2] = {};

  auto mfstep = [&](const u16* Asrc, f32x4 (*acc)[2]) {
    #pragma unroll
    for (int kk = 0; kk < 2; ++kk) {
      short8 a[4], bf[2];
      #pragma unroll
      for (int mi = 0; mi < 4; ++mi) {
        int m = wm * 64 + mi * 16 + cl;
        int ch = (kk * 4 + kq) ^ (m & 7);
        a[mi] = *(const short8*)(Asrc + m * 64 + ch * 8);
      }
      #pragma unroll
      for (int ni = 0; ni < 2; ++ni) {
        int n = wn * 32 + ni * 16 + cl;
        int ch = (kk * 4 + kq) ^ (n & 7);
        bf[ni] = *(const short8*)(Bs + n * 64 + ch * 8);
      }
      #pragma unroll
      for (int mi = 0; mi < 4; ++mi)
        #pragma unroll
        for (int ni = 0; ni < 2; ++ni)
          acc[mi][ni] = __builtin_amdgcn_mfma_f32_16x16x32_bf16(
              a[mi], bf[ni], acc[mi][ni], 0, 0, 0);
    }
  };

  stageB(Vbb, 128, 0);   __syncthreads();
  mfstep(As[0], accS);   __syncthreads();
  stageB(Vbb, 128, 64);  __syncthreads();
  mfstep(As[1], accS);   __syncthreads();
  stageB(Tbb, 256, 0);   __syncthreads();
  mfstep(As[0], accY);   __syncthreads();
  stageB(Tbb, 256, 64);  __syncthreads();
  mfstep(As[1], accY);

  // ---- in-register scan over c; accS becomes prev-state ----
  float sgn = (cl & 1) ? 1.f : -1.f;
  #pragma unroll
  for (int ni = 0; ni < 2; ++ni) {
    int n = (wn * 32 + ni * 16 + cl) >> 1;
    float wr = wLc[2 * (h * Nst + n)];
    float wi = wLc[2 * (h * Nst + n) + 1];
    float swi = sgn * wi;
    #pragma unroll
    for (int mi = 0; mi < 4; ++mi) {
      float carry = 0.f;
      #pragma unroll
      for (int c = 0; c < NC; ++c) {
        float part = __shfl_xor(carry, 1);
        float a_used = accS[mi][ni][c & 3];
        float Sc = fmaf(wr, carry, fmaf(swi, part, a_used));
        if (kq == (c >> 2)) accS[mi][ni][c & 3] = carry;   // prev-state
        carry = __shfl(Sc, ((c >> 2) << 4) + cl);
      }
    }
  }

  __syncthreads();   // all MFMA reads of As/Bs done
  // write prev-states bf16 into As region, swizzled as the fragment reads expect
  #pragma unroll
  for (int mi = 0; mi < 4; ++mi)
    #pragma unroll
    for (int ni = 0; ni < 2; ++ni) {
      int colv = wn * 32 + ni * 16 + cl;
      int half = colv >> 6, cv = colv & 63;
      #pragma unroll
      for (int r = 0; r < 4; ++r) {
        int m = wm * 64 + mi * 16 + kq * 4 + r;
        As[half][m * 64 + (((cv >> 3) ^ (m & 7)) << 3) + (cv & 7)] =
            f2b(accS[mi][ni][r]);
      }
    }
  stageB(Tbb, 256, 128);  __syncthreads();
  mfstep(As[0], accY);    __syncthreads();
  stageB(Tbb, 256, 192);  __syncthreads();
  mfstep(As[1], accY);

  #pragma unroll
  for (int mi = 0; mi < 4; ++mi)
    #pragma unroll
    for (int ni = 0; ni < 2; ++ni) {
      int t = wn * 32 + ni * 16 + cl;
      #pragma unroll
      for (int r = 0; r < 4; ++r) {
        int row = m0 + wm * 64 + mi * 16 + kq * 4 + r;
        float x = accY[mi][ni][r];
        float inner = 0.7978845608028654f * fmaf(0.044715f, x*x*x, x);
        float g = 0.5f * x * (1.f + tanhf(inner));
        ytb[((size_t)h * BC + row) * LC + t] = f2b(g);
      }
    }
}

// ---------------- trB: ytb (h, bc, t) -> ybb (bl, h) bf16 ----------------
__global__ __launch_bounds__(256) void trB_k(
    const u16* __restrict__ ytb, u16* __restrict__ ybb) {
  int bc = blockIdx.x;
  int h0 = blockIdx.y * 64;
  __shared__ float Lt[128][65];
  const u16* src = ytb + ((size_t)h0 * BC + bc) * LC;
  for (int it = 0; it < 16; ++it) {
    int idx = it * 256 + threadIdx.x;
    int hh = idx >> 6, tl = idx & 63;
    u32 v = *(const u32*)(src + (size_t)hh * BC * LC + 2 * tl);
    Lt[2*tl][hh]   = b2f((u16)(v & 0xffff));
    Lt[2*tl+1][hh] = b2f((u16)(v >> 16));
  }
  __syncthreads();
  for (int it = 0; it < 16; ++it) {
    int idx = it * 256 + threadIdx.x;
    int t = idx >> 5, hl = idx & 31;
    u32 lo = f2b(Lt[t][2*hl]);
    u32 hi = f2b(Lt[t][2*hl+1]);
    ((u32*)ybb)[((size_t)bc * LC + t) * (Hq / 2) + h0 / 2 + hl] = lo | (hi << 16);
  }
}

// ---------------- bf16 MFMA GEMM + bias + GLU + residual ----------------
__global__ __launch_bounds__(256) void gemm_k(
    const __hip_bfloat16* __restrict__ ybb, const __hip_bfloat16* __restrict__ Wb,
    const float* __restrict__ bout, float* __restrict__ hb) {
  __shared__ __hip_bfloat16 As[128 * 64];
  __shared__ __hip_bfloat16 Bs[128 * 64];
  int tid = threadIdx.x;
  int m0 = blockIdx.x * 128;
  int ot = blockIdx.y;
  int wid = tid >> 6, lane = tid & 63;
  int cl = lane & 15, kq = lane >> 4;
  f32x4 acc[2][8] = {};
  for (int kt = 0; kt < GK / 64; ++kt) {
    int k0 = kt * 64;
    #pragma unroll
    for (int q = 0; q < 4; ++q) {
      int idx = q * 256 + tid;
      int r = idx >> 3, ch = idx & 7;
      const __hip_bfloat16* sA =
          ybb + (size_t)(m0 + r) * GK + k0 + ((ch ^ (r & 7)) << 3);
      gload16(sA, (char*)As + (size_t)(q * 256 + (tid & ~63)) * 16);
      int wrow = ot * 64 + r + ((r >= 64) ? 192 : 0);
      const __hip_bfloat16* sB =
          Wb + (size_t)wrow * GK + k0 + ((ch ^ (r & 7)) << 3);
      gload16(sB, (char*)Bs + (size_t)(q * 256 + (tid & ~63)) * 16);
    }
    __syncthreads();
    #pragma unroll
    for (int kk = 0; kk < 2; ++kk) {
      short8 a[2], bfr[8];
      #pragma unroll
      for (int mi = 0; mi < 2; ++mi) {
        int m = wid * 32 + mi * 16 + cl;
        int ch = (kk * 4 + kq) ^ (m & 7);
        a[mi] = *(const short8*)(As + m * 64 + ch * 8);
      }
      #pragma unroll
      for (int ni = 0; ni < 8; ++ni) {
        int n = ni * 16 + cl;
        int ch = (kk * 4 + kq) ^ (n & 7);
        bfr[ni] = *(const short8*)(Bs + n * 64 + ch * 8);
      }
      #pragma unroll
      for (int mi = 0; mi < 2; ++mi)
        #pragma unroll
        for (int ni = 0; ni < 8; ++ni)
          acc[mi][ni] = __builtin_amdgcn_mfma_f32_16x16x32_bf16(
              a[mi], bfr[ni], acc[mi][ni], 0, 0, 0);
    }
    __syncthreads();
  }
  #pragma unroll
  for (int mi = 0; mi < 2; ++mi) {
    #pragma unroll
    for (int ni = 0; ni < 4; ++ni) {
      int o1 = ot * 64 + ni * 16 + cl;
      float b1 = bout[o1], b2 = bout[o1 + 256];
      #pragma unroll
      for (int r = 0; r < 4; ++r) {
        int row = m0 + wid * 32 + mi * 16 + kq * 4 + r;
        float z1 = acc[mi][ni][r] + b1;
        float z2 = acc[mi][ni + 4][r] + b2;
        float g = z1 / (1.f + expf(-z2));
        hb[(size_t)row * Hq + o1] += g;
      }
    }
  }
}

extern "C" void kernel_launch(void* const* d_in, const int* in_sizes, int n_in,
                              void* d_out, int out_size, void* d_ws, size_t ws_size,
                              hipStream_t stream) {
  (void)in_sizes; (void)n_in; (void)out_size; (void)ws_size;
  const float* x      = (const float*)d_in[0];
  const float* log_dt = (const float*)d_in[1];
  const float* Alog   = (const float*)d_in[2];
  const float* Aim    = (const float*)d_in[3];
  const float* Cre    = (const float*)d_in[4];
  const float* Cim    = (const float*)d_in[5];
  const float* Dv     = (const float*)d_in[6];
  const float* Wout   = (const float*)d_in[7];
  const float* bout   = (const float*)d_in[8];
  const float* lns    = (const float*)d_in[9];
  const float* lnb    = (const float*)d_in[10];

  float* hb = (float*)d_out;
  float* ws = (float*)d_ws;
  // aliases by liveness: znb (dead after trA) ∪ ybb (trB->gemm)
  u16* znb = (u16*)ws;                         // SZ ushort
  u16* ybb = znb;                              // alias
  u16* zt  = (u16*)(ws + SZ/2);                // SZ ushort
  u16* ytb = (u16*)(ws + SZ);                  // SZ ushort (conv out)
  float* p  = ws + SZ + SZ/2;
  u16* Vb  = (u16*)p; p += SZ/4;               // H*128*128 ushort
  u16* TRb = (u16*)p; p += SZ/2;               // H*128*256 ushort
  u16* Wb  = (u16*)p; p += (NL*2*Hq*Hq)/2;     // bf16 weights
  float* wv  = p;  p += 2*Hq*Nst;
  float* wLc = p;  p += 2*Hq*Nst;
  float* dA  = p;  p += 2*Hq*Nst;
  float* Cd  = p;  p += 2*Hq*Nst;
  float* Kt  = p;  p += Hq*LC;

  hipMemcpyAsync(hb, x, SZ * sizeof(float), hipMemcpyDeviceToDevice, stream);
  cvtw_k<<<(NL*2*Hq*Hq)/256, 256, 0, stream>>>(Wout, (__hip_bfloat16*)Wb, NL*2*Hq*Hq);

  for (int i = 0; i < NL; ++i) {
    paramA_k<<<(Hq*Nst)/256, 256, 0, stream>>>(
        log_dt + i*Hq, Alog + (size_t)i*Hq*Nst, Aim + (size_t)i*Hq*Nst,
        Cre + (size_t)i*Hq*Nst, Cim + (size_t)i*Hq*Nst, wv, wLc, dA, Cd);
    paramB_k<<<Hq, 64, 0, stream>>>(wv, Cd, Dv + i*Hq, Kt);
    paramM_k<<<Hq, 256, 0, stream>>>(dA, Cd, Kt, Vb, TRb);
    ln_k<<<(Bq*Lq)/4, 256, 0, stream>>>(hb, lns + i*Hq, lnb + i*Hq, znb);
    trA_k<<<dim3(BC, 4), 256, 0, stream>>>(znb, zt);
    s4core_k<<<dim3(2, Hq), 512, 0, stream>>>(zt, Vb, TRb, wLc, ytb);
    trB_k<<<dim3(BC, 4), 256, 0, stream>>>(ytb, ybb);
    gemm_k<<<dim3((Bq*Lq)/128, 4), 256, 0, stream>>>(
        (const __hip_bfloat16*)ybb,
        (const __hip_bfloat16*)(Wb + (size_t)i * 2 * Hq * Hq),   // layer offset!
        bout + (size_t)i*2*Hq, hb);
  }
}

// Round 8
// 362.964 us; speedup vs baseline: 6.5815x; 1.5472x over previous
//
#include <hip/hip_runtime.h>
#include <hip/hip_bf16.h>
#include <math.h>

#define Bq 16
#define Lq 2048
#define Hq 256
#define Nst 64
#define LC 128
#define NC 16
#define NL 4
#define BC 256   // Bq*NC
#define GK 256
#define SZ ((size_t)Bq * Lq * Hq)   // 8388608

typedef __attribute__((ext_vector_type(8))) short short8;
typedef __attribute__((ext_vector_type(4))) float f32x4;
typedef unsigned short u16;
typedef unsigned int u32;

__device__ __forceinline__ u16 f2b(float x) {
  __hip_bfloat16 b = __float2bfloat16(x);
  u16 u; __builtin_memcpy(&u, &b, 2); return u;
}
__device__ __forceinline__ float b2f(u16 u) {
  u32 t = ((u32)u) << 16; float f; __builtin_memcpy(&f, &t, 4); return f;
}
__device__ __forceinline__ void gload16(const void* g, void* l) {
  __builtin_amdgcn_global_load_lds(
      (const __attribute__((address_space(1))) void*)g,
      (__attribute__((address_space(3))) void*)l, 16, 0, 0);
}

// ---------------- paramA: all layers; gi = layer*16384 + h*64 + n ----------------
__global__ __launch_bounds__(256) void paramA_k(
    const float* __restrict__ log_dt, const float* __restrict__ Alog,
    const float* __restrict__ Aim, const float* __restrict__ Cre,
    const float* __restrict__ Cim,
    float* __restrict__ wv, float* __restrict__ wLc,
    float* __restrict__ dA, float* __restrict__ Cd) {
  int gi = blockIdx.x * blockDim.x + threadIdx.x;
  if (gi >= NL * Hq * Nst) return;
  int layer = gi >> 14;
  int h = (gi & 16383) >> 6;
  float dt = expf(log_dt[layer * Hq + h]);
  float ar = -expf(Alog[gi]);
  float ai = Aim[gi];
  float dr = ar * dt, di = ai * dt;
  dA[2*gi] = dr; dA[2*gi+1] = di;
  float er = expf(dr); float sn, cs; sincosf(di, &sn, &cs);
  float wr = er * cs, wi = er * sn;
  wv[2*gi] = wr; wv[2*gi+1] = wi;
  float e2 = expf(dr * (float)LC); float sn2, cs2; sincosf(di * (float)LC, &sn2, &cs2);
  wLc[2*gi] = e2 * cs2; wLc[2*gi+1] = e2 * sn2;
  float nr = wr - 1.f, ni = wi;
  float d2 = ar*ar + ai*ai;
  float qr = (nr*ar + ni*ai) / d2;
  float qi = (ni*ar - nr*ai) / d2;
  float cr = Cre[gi], ci = Cim[gi];
  Cd[2*gi]   = cr*qr - ci*qi;
  Cd[2*gi+1] = cr*qi + ci*qr;
}

// Kt[lh][m] = 2*Re(sum_n Cd w^m) (+ D folded into tap 0); lh = layer*Hq + h
__global__ __launch_bounds__(64) void paramB_k(
    const float* __restrict__ wv, const float* __restrict__ Cd,
    const float* __restrict__ Dv, float* __restrict__ Kt) {
  int lh = blockIdx.x, n = threadIdx.x;
  int i = lh * Nst + n;
  float wr = wv[2*i], wi = wv[2*i+1];
  float cr = Cd[2*i], ci = Cd[2*i+1];
  float pr = 1.f, pi = 0.f;
  for (int m = 0; m < LC; ++m) {
    float v = 2.f * (cr*pr - ci*pi);
    for (int off = 32; off; off >>= 1) v += __shfl_down(v, off);
    if (n == 0) Kt[lh * LC + m] = v + (m == 0 ? Dv[lh] : 0.f);
    float t = pr*wr - pi*wi;
    pi = fmaf(pr, wi, pi*wr);
    pr = t;
  }
}

// ---------------- paramM: Vb[lh][rr][j], TRb[lh][t][k] bf16, all layers ----------
__global__ __launch_bounds__(256) void paramM_k(
    const float* __restrict__ dA, const float* __restrict__ Cd,
    const float* __restrict__ Kt, u16* __restrict__ Vb, u16* __restrict__ TRb) {
  int lh = blockIdx.x;
  int wid = threadIdx.x >> 6, lane = threadIdx.x & 63;
  __shared__ float kts[LC];
  if (threadIdx.x < LC) kts[threadIdx.x] = Kt[lh * LC + threadIdx.x];
  __syncthreads();
  if (wid < 2) {
    for (int ro = 0; ro < 64; ++ro) {
      int rr = wid * 64 + ro;
      int n = rr >> 1, im = rr & 1;
      float dr = dA[(lh*Nst+n)*2], di = dA[(lh*Nst+n)*2+1];
      #pragma unroll
      for (int half = 0; half < 2; ++half) {
        int j = lane + half * 64;
        float p = (float)(127 - j);
        float e = expf(dr * p); float sn, cs; sincosf(di * p, &sn, &cs);
        Vb[((size_t)lh * 128 + rr) * 128 + j] = f2b(im ? e * sn : e * cs);
      }
    }
  } else {
    for (int to = 0; to < 64; ++to) {
      int t = (wid - 2) * 64 + to;
      #pragma unroll
      for (int half = 0; half < 2; ++half) {
        int j = lane + half * 64;
        float v = (j <= t) ? kts[t - j] : 0.f;
        TRb[((size_t)lh * 128 + t) * 256 + j] = f2b(v);
      }
      #pragma unroll
      for (int half = 0; half < 2; ++half) {
        int rr = lane + half * 64;
        int n = rr >> 1, im = rr & 1;
        float dr = dA[(lh*Nst+n)*2], di = dA[(lh*Nst+n)*2+1];
        float cr = Cd[(lh*Nst+n)*2], ci = Cd[(lh*Nst+n)*2+1];
        float p = (float)(t + 1);
        float e = expf(dr * p); float sn, cs; sincosf(di * p, &sn, &cs);
        float wpr = e * cs, wpi = e * sn;
        float qr = cr*wpr - ci*wpi, qi = cr*wpi + ci*wpr;
        TRb[((size_t)lh * 128 + t) * 256 + 128 + rr] = f2b(im ? -2.f*qi : 2.f*qr);
      }
    }
  }
}

// ---------------- W -> bf16 ----------------
__global__ __launch_bounds__(256) void cvtw_k(
    const float* __restrict__ w, __hip_bfloat16* __restrict__ wb, int n) {
  int i = blockIdx.x * 256 + threadIdx.x;
  if (i < n) wb[i] = __float2bfloat16(w[i]);
}

// ---------------- lntr: LN (over H) + transpose -> zt (h, bc, j) bf16 ----------
// Block (bc, jh): 64 rows j = jh*64 + 0..63 of chunk bc. LN per row (same math
// as verified ln_k), bf16 into padded LDS [j][h], transposed u32 writes to zt.
__global__ __launch_bounds__(512) void lntr_k(
    const float* __restrict__ src, const float* __restrict__ sc,
    const float* __restrict__ bi, u16* __restrict__ zt) {
  int bc = blockIdx.x, jh = blockIdx.y;
  __shared__ u16 Lt[64][Hq + 6];   // +6 pad: stride 131 dwords -> 2-way reads
  int wave = threadIdx.x >> 6, lane = threadIdx.x & 63;
  float4 scv = ((const float4*)sc)[lane];
  float4 biv = ((const float4*)bi)[lane];
  #pragma unroll
  for (int rr = 0; rr < 8; ++rr) {
    int j = wave * 8 + rr;
    size_t row = (size_t)bc * LC + jh * 64 + j;
    const float4 v = ((const float4*)(src + row * Hq))[lane];
    float s  = v.x + v.y + v.z + v.w;
    float s2 = v.x*v.x + v.y*v.y + v.z*v.z + v.w*v.w;
    for (int off = 32; off; off >>= 1) { s += __shfl_down(s, off); s2 += __shfl_down(s2, off); }
    s = __shfl(s, 0); s2 = __shfl(s2, 0);
    float mu = s * (1.f / Hq);
    float var = s2 * (1.f / Hq) - mu * mu;
    float r = rsqrtf(var + 1e-5f);
    u32 w0 = (u32)f2b((v.x - mu) * r * scv.x + biv.x)
           | ((u32)f2b((v.y - mu) * r * scv.y + biv.y) << 16);
    u32 w1 = (u32)f2b((v.z - mu) * r * scv.z + biv.z)
           | ((u32)f2b((v.w - mu) * r * scv.w + biv.w) << 16);
    *(u32*)&Lt[j][4 * lane]     = w0;
    *(u32*)&Lt[j][4 * lane + 2] = w1;
  }
  __syncthreads();
  #pragma unroll
  for (int it = 0; it < 16; ++it) {
    int idx = it * 512 + threadIdx.x;   // h*32 + jl
    int h = idx >> 5, jl = idx & 31;
    u32 lo = Lt[2*jl][h], hi = Lt[2*jl+1][h];
    ((u32*)zt)[((size_t)h * BC + bc) * 64 + jh * 32 + jl] = lo | (hi << 16);
  }
}

// ---------------- s4core: S_local MFMA + in-reg chunk scan + conv MFMA + GELU ----
__global__ __launch_bounds__(512) void s4core_k(
    const u16* __restrict__ zt, const u16* __restrict__ Vb,
    const u16* __restrict__ TRb, const float* __restrict__ wLc,
    u16* __restrict__ ytb) {
  int h = blockIdx.y;
  int m0 = blockIdx.x * 128;
  __shared__ u16 As[2][128 * 64];   // zt K-halves; later overwritten with Sprev
  __shared__ u16 Bs[128 * 64];
  int tid = threadIdx.x;
  int wid = tid >> 6, lane = tid & 63;
  int cl = lane & 15, kq = lane >> 4;
  int wm = wid & 1, wn = wid >> 1;

  const u16* Ab  = zt  + ((size_t)h * BC + m0) * 128;
  const u16* Vbb = Vb  + (size_t)h * 128 * 128;
  const u16* Tbb = TRb + (size_t)h * 128 * 256;

  #pragma unroll
  for (int half = 0; half < 2; ++half)
    #pragma unroll
    for (int q = 0; q < 2; ++q) {
      int idx = q * 512 + tid;
      int r = idx >> 3, ch = idx & 7;
      gload16(Ab + (size_t)r * 128 + half * 64 + ((ch ^ (r & 7)) << 3),
              (char*)As[half] + (size_t)(q * 512 + (tid & ~63)) * 16);
    }

  auto stageB = [&](const u16* base, int stride, int col0) {
    #pragma unroll
    for (int q = 0; q < 2; ++q) {
      int idx = q * 512 + tid;
      int r = idx >> 3, ch = idx & 7;
      gload16(base + (size_t)r * stride + col0 + ((ch ^ (r & 7)) << 3),
              (char*)Bs + (size_t)(q * 512 + (tid & ~63)) * 16);
    }
  };

  f32x4 accS[4][2] = {};
  f32x4 accY[4][2] = {};

  auto mfstep = [&](const u16* Asrc, f32x4 (*acc)[2]) {
    #pragma unroll
    for (int kk = 0; kk < 2; ++kk) {
      short8 a[4], bf[2];
      #pragma unroll
      for (int mi = 0; mi < 4; ++mi) {
        int m = wm * 64 + mi * 16 + cl;
        int ch = (kk * 4 + kq) ^ (m & 7);
        a[mi] = *(const short8*)(Asrc + m * 64 + ch * 8);
      }
      #pragma unroll
      for (int ni = 0; ni < 2; ++ni) {
        int n = wn * 32 + ni * 16 + cl;
        int ch = (kk * 4 + kq) ^ (n & 7);
        bf[ni] = *(const short8*)(Bs + n * 64 + ch * 8);
      }
      #pragma unroll
      for (int mi = 0; mi < 4; ++mi)
        #pragma unroll
        for (int ni = 0; ni < 2; ++ni)
          acc[mi][ni] = __builtin_amdgcn_mfma_f32_16x16x32_bf16(
              a[mi], bf[ni], acc[mi][ni], 0, 0, 0);
    }
  };

  stageB(Vbb, 128, 0);   __syncthreads();
  mfstep(As[0], accS);   __syncthreads();
  stageB(Vbb, 128, 64);  __syncthreads();
  mfstep(As[1], accS);   __syncthreads();
  stageB(Tbb, 256, 0);   __syncthreads();
  mfstep(As[0], accY);   __syncthreads();
  stageB(Tbb, 256, 64);  __syncthreads();
  mfstep(As[1], accY);

  // ---- in-register scan over c; accS becomes prev-state ----
  float sgn = (cl & 1) ? 1.f : -1.f;
  #pragma unroll
  for (int ni = 0; ni < 2; ++ni) {
    int n = (wn * 32 + ni * 16 + cl) >> 1;
    float wr = wLc[2 * (h * Nst + n)];
    float wi = wLc[2 * (h * Nst + n) + 1];
    float swi = sgn * wi;
    #pragma unroll
    for (int mi = 0; mi < 4; ++mi) {
      float carry = 0.f;
      #pragma unroll
      for (int c = 0; c < NC; ++c) {
        float part = __shfl_xor(carry, 1);
        float a_used = accS[mi][ni][c & 3];
        float Sc = fmaf(wr, carry, fmaf(swi, part, a_used));
        if (kq == (c >> 2)) accS[mi][ni][c & 3] = carry;   // prev-state
        carry = __shfl(Sc, ((c >> 2) << 4) + cl);
      }
    }
  }

  __syncthreads();
  #pragma unroll
  for (int mi = 0; mi < 4; ++mi)
    #pragma unroll
    for (int ni = 0; ni < 2; ++ni) {
      int colv = wn * 32 + ni * 16 + cl;
      int half = colv >> 6, cv = colv & 63;
      #pragma unroll
      for (int r = 0; r < 4; ++r) {
        int m = wm * 64 + mi * 16 + kq * 4 + r;
        As[half][m * 64 + (((cv >> 3) ^ (m & 7)) << 3) + (cv & 7)] =
            f2b(accS[mi][ni][r]);
      }
    }
  stageB(Tbb, 256, 128);  __syncthreads();
  mfstep(As[0], accY);    __syncthreads();
  stageB(Tbb, 256, 192);  __syncthreads();
  mfstep(As[1], accY);

  #pragma unroll
  for (int mi = 0; mi < 4; ++mi)
    #pragma unroll
    for (int ni = 0; ni < 2; ++ni) {
      int t = wn * 32 + ni * 16 + cl;
      #pragma unroll
      for (int r = 0; r < 4; ++r) {
        int row = m0 + wm * 64 + mi * 16 + kq * 4 + r;
        float x = accY[mi][ni][r];
        float inner = 0.7978845608028654f * fmaf(0.044715f, x*x*x, x);
        float g = 0.5f * x * (1.f + tanhf(inner));
        ytb[((size_t)h * BC + row) * LC + t] = f2b(g);
      }
    }
}

// ---------------- trB: ytb (h, bc, t) -> ybb (bl, h) bf16 ----------------
__global__ __launch_bounds__(256) void trB_k(
    const u16* __restrict__ ytb, u16* __restrict__ ybb) {
  int bc = blockIdx.x;
  int h0 = blockIdx.y * 64;
  __shared__ float Lt[128][65];
  const u16* src = ytb + ((size_t)h0 * BC + bc) * LC;
  for (int it = 0; it < 16; ++it) {
    int idx = it * 256 + threadIdx.x;
    int hh = idx >> 6, tl = idx & 63;
    u32 v = *(const u32*)(src + (size_t)hh * BC * LC + 2 * tl);
    Lt[2*tl][hh]   = b2f((u16)(v & 0xffff));
    Lt[2*tl+1][hh] = b2f((u16)(v >> 16));
  }
  __syncthreads();
  for (int it = 0; it < 16; ++it) {
    int idx = it * 256 + threadIdx.x;
    int t = idx >> 5, hl = idx & 31;
    u32 lo = f2b(Lt[t][2*hl]);
    u32 hi = f2b(Lt[t][2*hl+1]);
    ((u32*)ybb)[((size_t)bc * LC + t) * (Hq / 2) + h0 / 2 + hl] = lo | (hi << 16);
  }
}

// ---------------- bf16 MFMA GEMM + bias + GLU + residual(from rsrc) ----------
__global__ __launch_bounds__(256) void gemm_k(
    const __hip_bfloat16* __restrict__ ybb, const __hip_bfloat16* __restrict__ Wb,
    const float* __restrict__ bout, const float* __restrict__ rsrc,
    float* __restrict__ hb) {
  __shared__ __hip_bfloat16 As[128 * 64];
  __shared__ __hip_bfloat16 Bs[128 * 64];
  int tid = threadIdx.x;
  int m0 = blockIdx.x * 128;
  int ot = blockIdx.y;
  int wid = tid >> 6, lane = tid & 63;
  int cl = lane & 15, kq = lane >> 4;
  f32x4 acc[2][8] = {};
  for (int kt = 0; kt < GK / 64; ++kt) {
    int k0 = kt * 64;
    #pragma unroll
    for (int q = 0; q < 4; ++q) {
      int idx = q * 256 + tid;
      int r = idx >> 3, ch = idx & 7;
      const __hip_bfloat16* sA =
          ybb + (size_t)(m0 + r) * GK + k0 + ((ch ^ (r & 7)) << 3);
      gload16(sA, (char*)As + (size_t)(q * 256 + (tid & ~63)) * 16);
      int wrow = ot * 64 + r + ((r >= 64) ? 192 : 0);
      const __hip_bfloat16* sB =
          Wb + (size_t)wrow * GK + k0 + ((ch ^ (r & 7)) << 3);
      gload16(sB, (char*)Bs + (size_t)(q * 256 + (tid & ~63)) * 16);
    }
    __syncthreads();
    #pragma unroll
    for (int kk = 0; kk < 2; ++kk) {
      short8 a[2], bfr[8];
      #pragma unroll
      for (int mi = 0; mi < 2; ++mi) {
        int m = wid * 32 + mi * 16 + cl;
        int ch = (kk * 4 + kq) ^ (m & 7);
        a[mi] = *(const short8*)(As + m * 64 + ch * 8);
      }
      #pragma unroll
      for (int ni = 0; ni < 8; ++ni) {
        int n = ni * 16 + cl;
        int ch = (kk * 4 + kq) ^ (n & 7);
        bfr[ni] = *(const short8*)(Bs + n * 64 + ch * 8);
      }
      #pragma unroll
      for (int mi = 0; mi < 2; ++mi)
        #pragma unroll
        for (int ni = 0; ni < 8; ++ni)
          acc[mi][ni] = __builtin_amdgcn_mfma_f32_16x16x32_bf16(
              a[mi], bfr[ni], acc[mi][ni], 0, 0, 0);
    }
    __syncthreads();
  }
  #pragma unroll
  for (int mi = 0; mi < 2; ++mi) {
    #pragma unroll
    for (int ni = 0; ni < 4; ++ni) {
      int o1 = ot * 64 + ni * 16 + cl;
      float b1 = bout[o1], b2 = bout[o1 + 256];
      #pragma unroll
      for (int r = 0; r < 4; ++r) {
        int row = m0 + wid * 32 + mi * 16 + kq * 4 + r;
        float z1 = acc[mi][ni][r] + b1;
        float z2 = acc[mi][ni + 4][r] + b2;
        float g = z1 / (1.f + expf(-z2));
        size_t idx = (size_t)row * Hq + o1;
        hb[idx] = rsrc[idx] + g;
      }
    }
  }
}

extern "C" void kernel_launch(void* const* d_in, const int* in_sizes, int n_in,
                              void* d_out, int out_size, void* d_ws, size_t ws_size,
                              hipStream_t stream) {
  (void)in_sizes; (void)n_in; (void)out_size; (void)ws_size;
  const float* x      = (const float*)d_in[0];
  const float* log_dt = (const float*)d_in[1];
  const float* Alog   = (const float*)d_in[2];
  const float* Aim    = (const float*)d_in[3];
  const float* Cre    = (const float*)d_in[4];
  const float* Cim    = (const float*)d_in[5];
  const float* Dv     = (const float*)d_in[6];
  const float* Wout   = (const float*)d_in[7];
  const float* bout   = (const float*)d_in[8];
  const float* lns    = (const float*)d_in[9];
  const float* lnb    = (const float*)d_in[10];

  float* hb = (float*)d_out;
  float* p  = (float*)d_ws;
  u16* zt  = (u16*)p; p += SZ/2;               // (h, bc, j) bf16
  u16* ytb = (u16*)p; p += SZ/2;               // (h, bc, t) bf16
  u16* ybb = (u16*)p; p += SZ/2;               // (bl, h) bf16
  u16* Vb  = (u16*)p; p += SZ;                 // NL*Hq*128*128 u16
  u16* TRb = (u16*)p; p += 2*SZ;               // NL*Hq*128*256 u16
  u16* Wb  = (u16*)p; p += (NL*2*Hq*Hq)/2;     // bf16 weights, all layers
  float* wv  = p;  p += NL*2*Hq*Nst;
  float* wLc = p;  p += NL*2*Hq*Nst;
  float* dA  = p;  p += NL*2*Hq*Nst;
  float* Cd  = p;  p += NL*2*Hq*Nst;
  float* Kt  = p;  p += NL*Hq*LC;

  // params for ALL layers, hoisted out of the loop
  cvtw_k<<<(NL*2*Hq*Hq)/256, 256, 0, stream>>>(Wout, (__hip_bfloat16*)Wb, NL*2*Hq*Hq);
  paramA_k<<<(NL*Hq*Nst)/256, 256, 0, stream>>>(
      log_dt, Alog, Aim, Cre, Cim, wv, wLc, dA, Cd);
  paramB_k<<<NL*Hq, 64, 0, stream>>>(wv, Cd, Dv, Kt);
  paramM_k<<<NL*Hq, 256, 0, stream>>>(dA, Cd, Kt, Vb, TRb);

  for (int i = 0; i < NL; ++i) {
    const float* src = (i == 0) ? x : hb;
    lntr_k<<<dim3(BC, 2), 512, 0, stream>>>(src, lns + i*Hq, lnb + i*Hq, zt);
    s4core_k<<<dim3(2, Hq), 512, 0, stream>>>(
        zt, Vb + (size_t)i * Hq * 128 * 128, TRb + (size_t)i * Hq * 128 * 256,
        wLc + (size_t)i * 2 * Hq * Nst, ytb);
    trB_k<<<dim3(BC, 4), 256, 0, stream>>>(ytb, ybb);
    gemm_k<<<dim3((Bq*Lq)/128, 4), 256, 0, stream>>>(
        (const __hip_bfloat16*)ybb,
        (const __hip_bfloat16*)(Wb + (size_t)i * 2 * Hq * Hq),
        bout + (size_t)i*2*Hq, src, hb);
  }
}

// Round 9
// 306.919 us; speedup vs baseline: 7.7833x; 1.1826x over previous
//
#include <hip/hip_runtime.h>
#include <hip/hip_bf16.h>
#include <math.h>

#define Bq 16
#define Lq 2048
#define Hq 256
#define Nst 64
#define LC 128
#define NC 16
#define NL 4
#define BC 256   // Bq*NC
#define GK 256
#define PWS 133  // pw row stride: 133 % 32 = 5, coprime -> bank-clean
#define SZ ((size_t)Bq * Lq * Hq)   // 8388608

typedef __attribute__((ext_vector_type(8))) short short8;
typedef __attribute__((ext_vector_type(4))) float f32x4;
typedef unsigned short u16;
typedef unsigned int u32;

__device__ __forceinline__ u16 f2b(float x) {
  __hip_bfloat16 b = __float2bfloat16(x);
  u16 u; __builtin_memcpy(&u, &b, 2); return u;
}
__device__ __forceinline__ float b2f(u16 u) {
  u32 t = ((u32)u) << 16; float f; __builtin_memcpy(&f, &t, 4); return f;
}
__device__ __forceinline__ void gload16(const void* g, void* l) {
  __builtin_amdgcn_global_load_lds(
      (const __attribute__((address_space(1))) void*)g,
      (__attribute__((address_space(3))) void*)l, 16, 0, 0);
}

// ---------------- param_k: one block per (layer,h) = lh ----------------
// Builds pw[n][p] = w_n^p (p=0..128) in LDS via segmented recurrence
// (n-halves of 32 to fit LDS), then fills Vb/TRb bf16 + kts + wLc.
// Replaces paramA/paramB/paramM.
__global__ __launch_bounds__(256) void param_k(
    const float* __restrict__ log_dt, const float* __restrict__ Alog,
    const float* __restrict__ Aim, const float* __restrict__ Cre,
    const float* __restrict__ Cim, const float* __restrict__ Dv,
    u16* __restrict__ Vb, u16* __restrict__ TRb, float* __restrict__ wLc) {
  int lh = blockIdx.x;
  int tid = threadIdx.x;
  __shared__ float pwre[32][PWS], pwim[32][PWS];
  __shared__ float cdre[32], cdim[32];
  __shared__ float kacc[LC];
  __shared__ float kts[LC];
  int ln2 = tid & 31, pg = tid >> 5;   // n-in-half, power segment 0..7
  float dlt = expf(log_dt[lh]);

  for (int pass = 0; pass < 2; ++pass) {
    int n = pass * 32 + ln2;
    int gi = lh * Nst + n;
    float ar = -expf(Alog[gi]);
    float ai = Aim[gi];
    float dr = ar * dlt, di = ai * dlt;
    float er = expf(dr); float sn, cs; sincosf(di, &sn, &cs);
    float wr = er * cs, wi = er * sn;                 // w
    float p0 = (float)(16 * pg);
    float eb = expf(dr * p0); float sb, cb; sincosf(di * p0, &sb, &cb);
    float pr = eb * cb, pi = eb * sb;                 // w^(16*pg)
    #pragma unroll
    for (int s = 0; s < 16; ++s) {
      pwre[ln2][16*pg + s] = pr; pwim[ln2][16*pg + s] = pi;
      float t = pr*wr - pi*wi; pi = fmaf(pr, wi, pi*wr); pr = t;
    }
    if (pg == 7) {                                    // p = 128
      pwre[ln2][128] = pr; pwim[ln2][128] = pi;
      wLc[2*gi] = pr; wLc[2*gi+1] = pi;
    }
    if (pg == 0) {                                    // Cd = C*(w-1)/A
      float nr = wr - 1.f, ni = wi;
      float d2 = ar*ar + ai*ai;
      float qr = (nr*ar + ni*ai) / d2;
      float qi = (ni*ar - nr*ai) / d2;
      float cr = Cre[gi], ci = Cim[gi];
      cdre[ln2] = cr*qr - ci*qi;
      cdim[ln2] = cr*qi + ci*qr;
    }
    __syncthreads();
    // kts partial over this n-half
    if (tid < LC) {
      float s = 0.f;
      #pragma unroll
      for (int k = 0; k < 32; ++k)
        s = fmaf(cdre[k], pwre[k][tid], fmaf(-cdim[k], pwim[k][tid], s));
      if (pass == 0) kacc[tid] = s;
      else kts[tid] = 2.f * (kacc[tid] + s) + ((tid == 0) ? Dv[lh] : 0.f);
    }
    // V fill: rows rr in [64*pass, 64*pass+64);  V[rr][j] = w^(127-j) re/im
    #pragma unroll
    for (int it = 0; it < 32; ++it) {
      int idx = it * 256 + tid;
      int rl = idx >> 7, j = idx & 127;
      int nl = rl >> 1, im = rl & 1;
      int p = 127 - j;
      float v = im ? pwim[nl][p] : pwre[nl][p];
      Vb[((size_t)lh * 128 + 64*pass + rl) * 128 + j] = f2b(v);
    }
    // R fill: cols rr in [64*pass, ...); R[t][rr] = ±2*(Cd*w^(t+1)) re/im
    #pragma unroll
    for (int it = 0; it < 32; ++it) {
      int idx = it * 256 + tid;
      int t = idx >> 6, rl = idx & 63;
      int nl = rl >> 1, im = rl & 1;
      float wpr = pwre[nl][t+1], wpi = pwim[nl][t+1];
      float qr = cdre[nl]*wpr - cdim[nl]*wpi;
      float qi = cdre[nl]*wpi + cdim[nl]*wpr;
      TRb[((size_t)lh * 128 + t) * 256 + 128 + 64*pass + rl] =
          f2b(im ? -2.f*qi : 2.f*qr);
    }
    __syncthreads();   // fills done before table overwritten / kts final
  }
  // T fill: T[t][j] = kts[t-j] (kts complete after pass 1)
  #pragma unroll
  for (int it = 0; it < 64; ++it) {
    int idx = it * 256 + tid;
    int t = idx >> 7, j = idx & 127;
    TRb[((size_t)lh * 128 + t) * 256 + j] = f2b(j <= t ? kts[t - j] : 0.f);
  }
}

// ---------------- W -> bf16 ----------------
__global__ __launch_bounds__(256) void cvtw_k(
    const float* __restrict__ w, __hip_bfloat16* __restrict__ wb, int n) {
  int i = blockIdx.x * 256 + threadIdx.x;
  if (i < n) wb[i] = __float2bfloat16(w[i]);
}

// ---------------- lntr: LN (over H) + transpose -> zt (h, bc, j) bf16 ----------
__global__ __launch_bounds__(512) void lntr_k(
    const float* __restrict__ src, const float* __restrict__ sc,
    const float* __restrict__ bi, u16* __restrict__ zt) {
  int bc = blockIdx.x, jh = blockIdx.y;
  __shared__ u16 Lt[64][Hq + 6];
  int wave = threadIdx.x >> 6, lane = threadIdx.x & 63;
  float4 scv = ((const float4*)sc)[lane];
  float4 biv = ((const float4*)bi)[lane];
  #pragma unroll
  for (int rr = 0; rr < 8; ++rr) {
    int j = wave * 8 + rr;
    size_t row = (size_t)bc * LC + jh * 64 + j;
    const float4 v = ((const float4*)(src + row * Hq))[lane];
    float s  = v.x + v.y + v.z + v.w;
    float s2 = v.x*v.x + v.y*v.y + v.z*v.z + v.w*v.w;
    for (int off = 32; off; off >>= 1) { s += __shfl_down(s, off); s2 += __shfl_down(s2, off); }
    s = __shfl(s, 0); s2 = __shfl(s2, 0);
    float mu = s * (1.f / Hq);
    float var = s2 * (1.f / Hq) - mu * mu;
    float r = rsqrtf(var + 1e-5f);
    u32 w0 = (u32)f2b((v.x - mu) * r * scv.x + biv.x)
           | ((u32)f2b((v.y - mu) * r * scv.y + biv.y) << 16);
    u32 w1 = (u32)f2b((v.z - mu) * r * scv.z + biv.z)
           | ((u32)f2b((v.w - mu) * r * scv.w + biv.w) << 16);
    *(u32*)&Lt[j][4 * lane]     = w0;
    *(u32*)&Lt[j][4 * lane + 2] = w1;
  }
  __syncthreads();
  #pragma unroll
  for (int it = 0; it < 16; ++it) {
    int idx = it * 512 + threadIdx.x;   // h*32 + jl
    int h = idx >> 5, jl = idx & 31;
    u32 lo = Lt[2*jl][h], hi = Lt[2*jl+1][h];
    ((u32*)zt)[((size_t)h * BC + bc) * 64 + jh * 32 + jl] = lo | (hi << 16);
  }
}

// ---------------- s4core: S_local MFMA + in-reg chunk scan + conv MFMA + GELU ----
__global__ __launch_bounds__(512) void s4core_k(
    const u16* __restrict__ zt, const u16* __restrict__ Vb,
    const u16* __restrict__ TRb, const float* __restrict__ wLc,
    u16* __restrict__ ytb) {
  int h = blockIdx.y;
  int m0 = blockIdx.x * 128;
  __shared__ u16 As[2][128 * 64];
  __shared__ u16 Bs[128 * 64];
  int tid = threadIdx.x;
  int wid = tid >> 6, lane = tid & 63;
  int cl = lane & 15, kq = lane >> 4;
  int wm = wid & 1, wn = wid >> 1;

  const u16* Ab  = zt  + ((size_t)h * BC + m0) * 128;
  const u16* Vbb = Vb  + (size_t)h * 128 * 128;
  const u16* Tbb = TRb + (size_t)h * 128 * 256;

  #pragma unroll
  for (int half = 0; half < 2; ++half)
    #pragma unroll
    for (int q = 0; q < 2; ++q) {
      int idx = q * 512 + tid;
      int r = idx >> 3, ch = idx & 7;
      gload16(Ab + (size_t)r * 128 + half * 64 + ((ch ^ (r & 7)) << 3),
              (char*)As[half] + (size_t)(q * 512 + (tid & ~63)) * 16);
    }

  auto stageB = [&](const u16* base, int stride, int col0) {
    #pragma unroll
    for (int q = 0; q < 2; ++q) {
      int idx = q * 512 + tid;
      int r = idx >> 3, ch = idx & 7;
      gload16(base + (size_t)r * stride + col0 + ((ch ^ (r & 7)) << 3),
              (char*)Bs + (size_t)(q * 512 + (tid & ~63)) * 16);
    }
  };

  f32x4 accS[4][2] = {};
  f32x4 accY[4][2] = {};

  auto mfstep = [&](const u16* Asrc, f32x4 (*acc)[2]) {
    #pragma unroll
    for (int kk = 0; kk < 2; ++kk) {
      short8 a[4], bf[2];
      #pragma unroll
      for (int mi = 0; mi < 4; ++mi) {
        int m = wm * 64 + mi * 16 + cl;
        int ch = (kk * 4 + kq) ^ (m & 7);
        a[mi] = *(const short8*)(Asrc + m * 64 + ch * 8);
      }
      #pragma unroll
      for (int ni = 0; ni < 2; ++ni) {
        int n = wn * 32 + ni * 16 + cl;
        int ch = (kk * 4 + kq) ^ (n & 7);
        bf[ni] = *(const short8*)(Bs + n * 64 + ch * 8);
      }
      #pragma unroll
      for (int mi = 0; mi < 4; ++mi)
        #pragma unroll
        for (int ni = 0; ni < 2; ++ni)
          acc[mi][ni] = __builtin_amdgcn_mfma_f32_16x16x32_bf16(
              a[mi], bf[ni], acc[mi][ni], 0, 0, 0);
    }
  };

  stageB(Vbb, 128, 0);   __syncthreads();
  mfstep(As[0], accS);   __syncthreads();
  stageB(Vbb, 128, 64);  __syncthreads();
  mfstep(As[1], accS);   __syncthreads();
  stageB(Tbb, 256, 0);   __syncthreads();
  mfstep(As[0], accY);   __syncthreads();
  stageB(Tbb, 256, 64);  __syncthreads();
  mfstep(As[1], accY);

  // ---- in-register scan over c; accS becomes prev-state ----
  float sgn = (cl & 1) ? 1.f : -1.f;
  #pragma unroll
  for (int ni = 0; ni < 2; ++ni) {
    int n = (wn * 32 + ni * 16 + cl) >> 1;
    float wr = wLc[2 * (h * Nst + n)];
    float wi = wLc[2 * (h * Nst + n) + 1];
    float swi = sgn * wi;
    #pragma unroll
    for (int mi = 0; mi < 4; ++mi) {
      float carry = 0.f;
      #pragma unroll
      for (int c = 0; c < NC; ++c) {
        float part = __shfl_xor(carry, 1);
        float a_used = accS[mi][ni][c & 3];
        float Sc = fmaf(wr, carry, fmaf(swi, part, a_used));
        if (kq == (c >> 2)) accS[mi][ni][c & 3] = carry;   // prev-state
        carry = __shfl(Sc, ((c >> 2) << 4) + cl);
      }
    }
  }

  __syncthreads();
  #pragma unroll
  for (int mi = 0; mi < 4; ++mi)
    #pragma unroll
    for (int ni = 0; ni < 2; ++ni) {
      int colv = wn * 32 + ni * 16 + cl;
      int half = colv >> 6, cv = colv & 63;
      #pragma unroll
      for (int r = 0; r < 4; ++r) {
        int m = wm * 64 + mi * 16 + kq * 4 + r;
        As[half][m * 64 + (((cv >> 3) ^ (m & 7)) << 3) + (cv & 7)] =
            f2b(accS[mi][ni][r]);
      }
    }
  stageB(Tbb, 256, 128);  __syncthreads();
  mfstep(As[0], accY);    __syncthreads();
  stageB(Tbb, 256, 192);  __syncthreads();
  mfstep(As[1], accY);

  #pragma unroll
  for (int mi = 0; mi < 4; ++mi)
    #pragma unroll
    for (int ni = 0; ni < 2; ++ni) {
      int t = wn * 32 + ni * 16 + cl;
      #pragma unroll
      for (int r = 0; r < 4; ++r) {
        int row = m0 + wm * 64 + mi * 16 + kq * 4 + r;
        float x = accY[mi][ni][r];
        float inner = 0.7978845608028654f * fmaf(0.044715f, x*x*x, x);
        float g = 0.5f * x * (1.f + tanhf(inner));
        ytb[((size_t)h * BC + row) * LC + t] = f2b(g);
      }
    }
}

// ---------------- trB: ytb (h, bc, t) -> ybb (bl, h) bf16 ----------------
__global__ __launch_bounds__(256) void trB_k(
    const u16* __restrict__ ytb, u16* __restrict__ ybb) {
  int bc = blockIdx.x;
  int h0 = blockIdx.y * 64;
  __shared__ float Lt[128][65];
  const u16* src = ytb + ((size_t)h0 * BC + bc) * LC;
  for (int it = 0; it < 16; ++it) {
    int idx = it * 256 + threadIdx.x;
    int hh = idx >> 6, tl = idx & 63;
    u32 v = *(const u32*)(src + (size_t)hh * BC * LC + 2 * tl);
    Lt[2*tl][hh]   = b2f((u16)(v & 0xffff));
    Lt[2*tl+1][hh] = b2f((u16)(v >> 16));
  }
  __syncthreads();
  for (int it = 0; it < 16; ++it) {
    int idx = it * 256 + threadIdx.x;
    int t = idx >> 5, hl = idx & 31;
    u32 lo = f2b(Lt[t][2*hl]);
    u32 hi = f2b(Lt[t][2*hl+1]);
    ((u32*)ybb)[((size_t)bc * LC + t) * (Hq / 2) + h0 / 2 + hl] = lo | (hi << 16);
  }
}

// ---------------- bf16 MFMA GEMM + bias + GLU + residual(from rsrc) ----------
__global__ __launch_bounds__(256) void gemm_k(
    const __hip_bfloat16* __restrict__ ybb, const __hip_bfloat16* __restrict__ Wb,
    const float* __restrict__ bout, const float* __restrict__ rsrc,
    float* __restrict__ hb) {
  __shared__ __hip_bfloat16 As[128 * 64];
  __shared__ __hip_bfloat16 Bs[128 * 64];
  int tid = threadIdx.x;
  int m0 = blockIdx.x * 128;
  int ot = blockIdx.y;
  int wid = tid >> 6, lane = tid & 63;
  int cl = lane & 15, kq = lane >> 4;
  f32x4 acc[2][8] = {};
  for (int kt = 0; kt < GK / 64; ++kt) {
    int k0 = kt * 64;
    #pragma unroll
    for (int q = 0; q < 4; ++q) {
      int idx = q * 256 + tid;
      int r = idx >> 3, ch = idx & 7;
      const __hip_bfloat16* sA =
          ybb + (size_t)(m0 + r) * GK + k0 + ((ch ^ (r & 7)) << 3);
      gload16(sA, (char*)As + (size_t)(q * 256 + (tid & ~63)) * 16);
      int wrow = ot * 64 + r + ((r >= 64) ? 192 : 0);
      const __hip_bfloat16* sB =
          Wb + (size_t)wrow * GK + k0 + ((ch ^ (r & 7)) << 3);
      gload16(sB, (char*)Bs + (size_t)(q * 256 + (tid & ~63)) * 16);
    }
    __syncthreads();
    #pragma unroll
    for (int kk = 0; kk < 2; ++kk) {
      short8 a[2], bfr[8];
      #pragma unroll
      for (int mi = 0; mi < 2; ++mi) {
        int m = wid * 32 + mi * 16 + cl;
        int ch = (kk * 4 + kq) ^ (m & 7);
        a[mi] = *(const short8*)(As + m * 64 + ch * 8);
      }
      #pragma unroll
      for (int ni = 0; ni < 8; ++ni) {
        int n = ni * 16 + cl;
        int ch = (kk * 4 + kq) ^ (n & 7);
        bfr[ni] = *(const short8*)(Bs + n * 64 + ch * 8);
      }
      #pragma unroll
      for (int mi = 0; mi < 2; ++mi)
        #pragma unroll
        for (int ni = 0; ni < 8; ++ni)
          acc[mi][ni] = __builtin_amdgcn_mfma_f32_16x16x32_bf16(
              a[mi], bfr[ni], acc[mi][ni], 0, 0, 0);
    }
    __syncthreads();
  }
  #pragma unroll
  for (int mi = 0; mi < 2; ++mi) {
    #pragma unroll
    for (int ni = 0; ni < 4; ++ni) {
      int o1 = ot * 64 + ni * 16 + cl;
      float b1 = bout[o1], b2 = bout[o1 + 256];
      #pragma unroll
      for (int r = 0; r < 4; ++r) {
        int row = m0 + wid * 32 + mi * 16 + kq * 4 + r;
        float z1 = acc[mi][ni][r] + b1;
        float z2 = acc[mi][ni + 4][r] + b2;
        float g = z1 / (1.f + expf(-z2));
        size_t idx = (size_t)row * Hq + o1;
        hb[idx] = rsrc[idx] + g;
      }
    }
  }
}

extern "C" void kernel_launch(void* const* d_in, const int* in_sizes, int n_in,
                              void* d_out, int out_size, void* d_ws, size_t ws_size,
                              hipStream_t stream) {
  (void)in_sizes; (void)n_in; (void)out_size; (void)ws_size;
  const float* x      = (const float*)d_in[0];
  const float* log_dt = (const float*)d_in[1];
  const float* Alog   = (const float*)d_in[2];
  const float* Aim    = (const float*)d_in[3];
  const float* Cre    = (const float*)d_in[4];
  const float* Cim    = (const float*)d_in[5];
  const float* Dv     = (const float*)d_in[6];
  const float* Wout   = (const float*)d_in[7];
  const float* bout   = (const float*)d_in[8];
  const float* lns    = (const float*)d_in[9];
  const float* lnb    = (const float*)d_in[10];

  float* hb = (float*)d_out;
  float* p  = (float*)d_ws;
  u16* zt  = (u16*)p; p += SZ/2;               // (h, bc, j) bf16
  u16* ytb = (u16*)p; p += SZ/2;               // (h, bc, t) bf16
  u16* ybb = (u16*)p; p += SZ/2;               // (bl, h) bf16
  u16* Vb  = (u16*)p; p += SZ;                 // NL*Hq*128*128 u16
  u16* TRb = (u16*)p; p += 2*SZ;               // NL*Hq*128*256 u16
  u16* Wb  = (u16*)p; p += (NL*2*Hq*Hq)/2;     // bf16 weights, all layers
  float* wLc = p;  p += NL*2*Hq*Nst;

  // params for ALL layers: single kernel
  cvtw_k<<<(NL*2*Hq*Hq)/256, 256, 0, stream>>>(Wout, (__hip_bfloat16*)Wb, NL*2*Hq*Hq);
  param_k<<<NL*Hq, 256, 0, stream>>>(log_dt, Alog, Aim, Cre, Cim, Dv, Vb, TRb, wLc);

  for (int i = 0; i < NL; ++i) {
    const float* src = (i == 0) ? x : hb;
    lntr_k<<<dim3(BC, 2), 512, 0, stream>>>(src, lns + i*Hq, lnb + i*Hq, zt);
    s4core_k<<<dim3(2, Hq), 512, 0, stream>>>(
        zt, Vb + (size_t)i * Hq * 128 * 128, TRb + (size_t)i * Hq * 128 * 256,
        wLc + (size_t)i * 2 * Hq * Nst, ytb);
    trB_k<<<dim3(BC, 4), 256, 0, stream>>>(ytb, ybb);
    gemm_k<<<dim3((Bq*Lq)/128, 4), 256, 0, stream>>>(
        (const __hip_bfloat16*)ybb,
        (const __hip_bfloat16*)(Wb + (size_t)i * 2 * Hq * Hq),
        bout + (size_t)i*2*Hq, src, hb);
  }
}

// Round 10
// 303.961 us; speedup vs baseline: 7.8591x; 1.0097x over previous
//
#include <hip/hip_runtime.h>
#include <hip/hip_bf16.h>
#include <math.h>

#define Bq 16
#define Lq 2048
#define Hq 256
#define Nst 64
#define LC 128
#define NC 16
#define NL 4
#define BC 256   // Bq*NC
#define GK 256
#define PWS 133  // pw row stride: 133 % 32 = 5, coprime -> bank-clean
#define SZ ((size_t)Bq * Lq * Hq)   // 8388608

typedef __attribute__((ext_vector_type(8))) short short8;
typedef __attribute__((ext_vector_type(4))) float f32x4;
typedef unsigned short u16;
typedef unsigned int u32;

__device__ __forceinline__ u16 f2b(float x) {
  __hip_bfloat16 b = __float2bfloat16(x);
  u16 u; __builtin_memcpy(&u, &b, 2); return u;
}
__device__ __forceinline__ float b2f(u16 u) {
  u32 t = ((u32)u) << 16; float f; __builtin_memcpy(&f, &t, 4); return f;
}
__device__ __forceinline__ void gload16(const void* g, void* l) {
  __builtin_amdgcn_global_load_lds(
      (const __attribute__((address_space(1))) void*)g,
      (__attribute__((address_space(3))) void*)l, 16, 0, 0);
}

// ---------------- param_k: one block per (layer,h) = lh ----------------
// Builds pw[n][p] = w_n^p (p=0..128) in LDS via segmented recurrence
// (n-halves of 32 to fit LDS), then fills Vb/TRb bf16 + kts + wLc.
// All global fills are paired u32 stores (2 bf16/store, 256B/wave).
__global__ __launch_bounds__(256) void param_k(
    const float* __restrict__ log_dt, const float* __restrict__ Alog,
    const float* __restrict__ Aim, const float* __restrict__ Cre,
    const float* __restrict__ Cim, const float* __restrict__ Dv,
    u16* __restrict__ Vb, u16* __restrict__ TRb, float* __restrict__ wLc) {
  int lh = blockIdx.x;
  int tid = threadIdx.x;
  __shared__ float pwre[32][PWS], pwim[32][PWS];
  __shared__ float cdre[32], cdim[32];
  __shared__ float kacc[LC];
  __shared__ float kts[LC];
  int ln2 = tid & 31, pg = tid >> 5;   // n-in-half, power segment 0..7
  float dlt = expf(log_dt[lh]);

  for (int pass = 0; pass < 2; ++pass) {
    int n = pass * 32 + ln2;
    int gi = lh * Nst + n;
    float ar = -expf(Alog[gi]);
    float ai = Aim[gi];
    float dr = ar * dlt, di = ai * dlt;
    float er = expf(dr); float sn, cs; sincosf(di, &sn, &cs);
    float wr = er * cs, wi = er * sn;                 // w
    float p0 = (float)(16 * pg);
    float eb = expf(dr * p0); float sb, cb; sincosf(di * p0, &sb, &cb);
    float pr = eb * cb, pi = eb * sb;                 // w^(16*pg)
    #pragma unroll
    for (int s = 0; s < 16; ++s) {
      pwre[ln2][16*pg + s] = pr; pwim[ln2][16*pg + s] = pi;
      float t = pr*wr - pi*wi; pi = fmaf(pr, wi, pi*wr); pr = t;
    }
    if (pg == 7) {                                    // p = 128
      pwre[ln2][128] = pr; pwim[ln2][128] = pi;
      wLc[2*gi] = pr; wLc[2*gi+1] = pi;
    }
    if (pg == 0) {                                    // Cd = C*(w-1)/A
      float nr = wr - 1.f, ni = wi;
      float d2 = ar*ar + ai*ai;
      float qr = (nr*ar + ni*ai) / d2;
      float qi = (ni*ar - nr*ai) / d2;
      float cr = Cre[gi], ci = Cim[gi];
      cdre[ln2] = cr*qr - ci*qi;
      cdim[ln2] = cr*qi + ci*qr;
    }
    __syncthreads();
    // kts partial over this n-half
    if (tid < LC) {
      float s = 0.f;
      #pragma unroll
      for (int k = 0; k < 32; ++k)
        s = fmaf(cdre[k], pwre[k][tid], fmaf(-cdim[k], pwim[k][tid], s));
      if (pass == 0) kacc[tid] = s;
      else kts[tid] = 2.f * (kacc[tid] + s) + ((tid == 0) ? Dv[lh] : 0.f);
    }
    // V fill (u32-paired j): rows rr in [64*pass, 64*pass+64)
    #pragma unroll
    for (int it = 0; it < 16; ++it) {
      int idx = it * 256 + tid;          // [0, 4096) u32s
      int rl = idx >> 6, jw = idx & 63;
      int nl = rl >> 1, im = rl & 1;
      int pj = 127 - 2 * jw;             // power for even j; odd j is pj-1
      const float* row = im ? pwim[nl] : pwre[nl];
      u32 lo = f2b(row[pj]);
      u32 hi = f2b(row[pj - 1]);
      ((u32*)Vb)[(((size_t)lh * 128 + 64*pass + rl) * 128 + 2*jw) >> 1] =
          lo | (hi << 16);
    }
    // R fill (u32-paired re/im of same n): cols rr in [64*pass, ...)
    #pragma unroll
    for (int it = 0; it < 16; ++it) {
      int idx = it * 256 + tid;          // [0, 4096) u32s
      int t = idx >> 5, rw = idx & 31;
      float wpr = pwre[rw][t+1], wpi = pwim[rw][t+1];
      float qr = cdre[rw]*wpr - cdim[rw]*wpi;
      float qi = cdre[rw]*wpi + cdim[rw]*wpr;
      u32 lo = f2b(2.f * qr);
      u32 hi = f2b(-2.f * qi);
      ((u32*)TRb)[(((size_t)lh * 128 + t) * 256 + 128 + 64*pass + 2*rw) >> 1] =
          lo | (hi << 16);
    }
    __syncthreads();   // fills done before table overwritten / kts final
  }
  // T fill (u32-paired j): T[t][j] = kts[t-j], upper triangle zero
  #pragma unroll
  for (int it = 0; it < 32; ++it) {
    int idx = it * 256 + tid;            // [0, 8192) u32s
    int t = idx >> 6, jw = idx & 63;
    int j0 = 2 * jw;
    u32 lo = (j0     <= t) ? (u32)f2b(kts[t - j0])     : 0u;
    u32 hi = (j0 + 1 <= t) ? (u32)f2b(kts[t - j0 - 1]) : 0u;
    ((u32*)TRb)[(((size_t)lh * 128 + t) * 256 + j0) >> 1] = lo | (hi << 16);
  }
}

// ---------------- W -> bf16 ----------------
__global__ __launch_bounds__(256) void cvtw_k(
    const float* __restrict__ w, __hip_bfloat16* __restrict__ wb, int n) {
  int i = blockIdx.x * 256 + threadIdx.x;
  if (i < n) wb[i] = __float2bfloat16(w[i]);
}

// ---------------- lntr: LN (over H) + transpose -> zt (h, bc, j) bf16 ----------
__global__ __launch_bounds__(512) void lntr_k(
    const float* __restrict__ src, const float* __restrict__ sc,
    const float* __restrict__ bi, u16* __restrict__ zt) {
  int bc = blockIdx.x, jh = blockIdx.y;
  __shared__ u16 Lt[64][Hq + 6];
  int wave = threadIdx.x >> 6, lane = threadIdx.x & 63;
  float4 scv = ((const float4*)sc)[lane];
  float4 biv = ((const float4*)bi)[lane];
  #pragma unroll
  for (int rr = 0; rr < 8; ++rr) {
    int j = wave * 8 + rr;
    size_t row = (size_t)bc * LC + jh * 64 + j;
    const float4 v = ((const float4*)(src + row * Hq))[lane];
    float s  = v.x + v.y + v.z + v.w;
    float s2 = v.x*v.x + v.y*v.y + v.z*v.z + v.w*v.w;
    for (int off = 32; off; off >>= 1) { s += __shfl_down(s, off); s2 += __shfl_down(s2, off); }
    s = __shfl(s, 0); s2 = __shfl(s2, 0);
    float mu = s * (1.f / Hq);
    float var = s2 * (1.f / Hq) - mu * mu;
    float r = rsqrtf(var + 1e-5f);
    u32 w0 = (u32)f2b((v.x - mu) * r * scv.x + biv.x)
           | ((u32)f2b((v.y - mu) * r * scv.y + biv.y) << 16);
    u32 w1 = (u32)f2b((v.z - mu) * r * scv.z + biv.z)
           | ((u32)f2b((v.w - mu) * r * scv.w + biv.w) << 16);
    *(u32*)&Lt[j][4 * lane]     = w0;
    *(u32*)&Lt[j][4 * lane + 2] = w1;
  }
  __syncthreads();
  #pragma unroll
  for (int it = 0; it < 16; ++it) {
    int idx = it * 512 + threadIdx.x;   // h*32 + jl
    int h = idx >> 5, jl = idx & 31;
    u32 lo = Lt[2*jl][h], hi = Lt[2*jl+1][h];
    ((u32*)zt)[((size_t)h * BC + bc) * 64 + jh * 32 + jl] = lo | (hi << 16);
  }
}

// ---------------- s4core: S_local MFMA + in-reg chunk scan + conv MFMA + GELU ----
__global__ __launch_bounds__(512) void s4core_k(
    const u16* __restrict__ zt, const u16* __restrict__ Vb,
    const u16* __restrict__ TRb, const float* __restrict__ wLc,
    u16* __restrict__ ytb) {
  int h = blockIdx.y;
  int m0 = blockIdx.x * 128;
  __shared__ u16 As[2][128 * 64];
  __shared__ u16 Bs[128 * 64];
  int tid = threadIdx.x;
  int wid = tid >> 6, lane = tid & 63;
  int cl = lane & 15, kq = lane >> 4;
  int wm = wid & 1, wn = wid >> 1;

  const u16* Ab  = zt  + ((size_t)h * BC + m0) * 128;
  const u16* Vbb = Vb  + (size_t)h * 128 * 128;
  const u16* Tbb = TRb + (size_t)h * 128 * 256;

  #pragma unroll
  for (int half = 0; half < 2; ++half)
    #pragma unroll
    for (int q = 0; q < 2; ++q) {
      int idx = q * 512 + tid;
      int r = idx >> 3, ch = idx & 7;
      gload16(Ab + (size_t)r * 128 + half * 64 + ((ch ^ (r & 7)) << 3),
              (char*)As[half] + (size_t)(q * 512 + (tid & ~63)) * 16);
    }

  auto stageB = [&](const u16* base, int stride, int col0) {
    #pragma unroll
    for (int q = 0; q < 2; ++q) {
      int idx = q * 512 + tid;
      int r = idx >> 3, ch = idx & 7;
      gload16(base + (size_t)r * stride + col0 + ((ch ^ (r & 7)) << 3),
              (char*)Bs + (size_t)(q * 512 + (tid & ~63)) * 16);
    }
  };

  f32x4 accS[4][2] = {};
  f32x4 accY[4][2] = {};

  auto mfstep = [&](const u16* Asrc, f32x4 (*acc)[2]) {
    #pragma unroll
    for (int kk = 0; kk < 2; ++kk) {
      short8 a[4], bf[2];
      #pragma unroll
      for (int mi = 0; mi < 4; ++mi) {
        int m = wm * 64 + mi * 16 + cl;
        int ch = (kk * 4 + kq) ^ (m & 7);
        a[mi] = *(const short8*)(Asrc + m * 64 + ch * 8);
      }
      #pragma unroll
      for (int ni = 0; ni < 2; ++ni) {
        int n = wn * 32 + ni * 16 + cl;
        int ch = (kk * 4 + kq) ^ (n & 7);
        bf[ni] = *(const short8*)(Bs + n * 64 + ch * 8);
      }
      #pragma unroll
      for (int mi = 0; mi < 4; ++mi)
        #pragma unroll
        for (int ni = 0; ni < 2; ++ni)
          acc[mi][ni] = __builtin_amdgcn_mfma_f32_16x16x32_bf16(
              a[mi], bf[ni], acc[mi][ni], 0, 0, 0);
    }
  };

  stageB(Vbb, 128, 0);   __syncthreads();
  mfstep(As[0], accS);   __syncthreads();
  stageB(Vbb, 128, 64);  __syncthreads();
  mfstep(As[1], accS);   __syncthreads();
  stageB(Tbb, 256, 0);   __syncthreads();
  mfstep(As[0], accY);   __syncthreads();
  stageB(Tbb, 256, 64);  __syncthreads();
  mfstep(As[1], accY);

  // ---- in-register scan over c; accS becomes prev-state ----
  float sgn = (cl & 1) ? 1.f : -1.f;
  #pragma unroll
  for (int ni = 0; ni < 2; ++ni) {
    int n = (wn * 32 + ni * 16 + cl) >> 1;
    float wr = wLc[2 * (h * Nst + n)];
    float wi = wLc[2 * (h * Nst + n) + 1];
    float swi = sgn * wi;
    #pragma unroll
    for (int mi = 0; mi < 4; ++mi) {
      float carry = 0.f;
      #pragma unroll
      for (int c = 0; c < NC; ++c) {
        float part = __shfl_xor(carry, 1);
        float a_used = accS[mi][ni][c & 3];
        float Sc = fmaf(wr, carry, fmaf(swi, part, a_used));
        if (kq == (c >> 2)) accS[mi][ni][c & 3] = carry;   // prev-state
        carry = __shfl(Sc, ((c >> 2) << 4) + cl);
      }
    }
  }

  __syncthreads();
  #pragma unroll
  for (int mi = 0; mi < 4; ++mi)
    #pragma unroll
    for (int ni = 0; ni < 2; ++ni) {
      int colv = wn * 32 + ni * 16 + cl;
      int half = colv >> 6, cv = colv & 63;
      #pragma unroll
      for (int r = 0; r < 4; ++r) {
        int m = wm * 64 + mi * 16 + kq * 4 + r;
        As[half][m * 64 + (((cv >> 3) ^ (m & 7)) << 3) + (cv & 7)] =
            f2b(accS[mi][ni][r]);
      }
    }
  stageB(Tbb, 256, 128);  __syncthreads();
  mfstep(As[0], accY);    __syncthreads();
  stageB(Tbb, 256, 192);  __syncthreads();
  mfstep(As[1], accY);

  #pragma unroll
  for (int mi = 0; mi < 4; ++mi)
    #pragma unroll
    for (int ni = 0; ni < 2; ++ni) {
      int t = wn * 32 + ni * 16 + cl;
      #pragma unroll
      for (int r = 0; r < 4; ++r) {
        int row = m0 + wm * 64 + mi * 16 + kq * 4 + r;
        float x = accY[mi][ni][r];
        float inner = 0.7978845608028654f * fmaf(0.044715f, x*x*x, x);
        float g = 0.5f * x * (1.f + tanhf(inner));
        ytb[((size_t)h * BC + row) * LC + t] = f2b(g);
      }
    }
}

// ---------------- trB: ytb (h, bc, t) -> ybb (bl, h) bf16 ----------------
__global__ __launch_bounds__(256) void trB_k(
    const u16* __restrict__ ytb, u16* __restrict__ ybb) {
  int bc = blockIdx.x;
  int h0 = blockIdx.y * 64;
  __shared__ float Lt[128][65];
  const u16* src = ytb + ((size_t)h0 * BC + bc) * LC;
  for (int it = 0; it < 16; ++it) {
    int idx = it * 256 + threadIdx.x;
    int hh = idx >> 6, tl = idx & 63;
    u32 v = *(const u32*)(src + (size_t)hh * BC * LC + 2 * tl);
    Lt[2*tl][hh]   = b2f((u16)(v & 0xffff));
    Lt[2*tl+1][hh] = b2f((u16)(v >> 16));
  }
  __syncthreads();
  for (int it = 0; it < 16; ++it) {
    int idx = it * 256 + threadIdx.x;
    int t = idx >> 5, hl = idx & 31;
    u32 lo = f2b(Lt[t][2*hl]);
    u32 hi = f2b(Lt[t][2*hl+1]);
    ((u32*)ybb)[((size_t)bc * LC + t) * (Hq / 2) + h0 / 2 + hl] = lo | (hi << 16);
  }
}

// ---------------- bf16 MFMA GEMM + bias + GLU + residual(from rsrc) ----------
__global__ __launch_bounds__(256) void gemm_k(
    const __hip_bfloat16* __restrict__ ybb, const __hip_bfloat16* __restrict__ Wb,
    const float* __restrict__ bout, const float* __restrict__ rsrc,
    float* __restrict__ hb) {
  __shared__ __hip_bfloat16 As[128 * 64];
  __shared__ __hip_bfloat16 Bs[128 * 64];
  int tid = threadIdx.x;
  int m0 = blockIdx.x * 128;
  int ot = blockIdx.y;
  int wid = tid >> 6, lane = tid & 63;
  int cl = lane & 15, kq = lane >> 4;
  f32x4 acc[2][8] = {};
  for (int kt = 0; kt < GK / 64; ++kt) {
    int k0 = kt * 64;
    #pragma unroll
    for (int q = 0; q < 4; ++q) {
      int idx = q * 256 + tid;
      int r = idx >> 3, ch = idx & 7;
      const __hip_bfloat16* sA =
          ybb + (size_t)(m0 + r) * GK + k0 + ((ch ^ (r & 7)) << 3);
      gload16(sA, (char*)As + (size_t)(q * 256 + (tid & ~63)) * 16);
      int wrow = ot * 64 + r + ((r >= 64) ? 192 : 0);
      const __hip_bfloat16* sB =
          Wb + (size_t)wrow * GK + k0 + ((ch ^ (r & 7)) << 3);
      gload16(sB, (char*)Bs + (size_t)(q * 256 + (tid & ~63)) * 16);
    }
    __syncthreads();
    #pragma unroll
    for (int kk = 0; kk < 2; ++kk) {
      short8 a[2], bfr[8];
      #pragma unroll
      for (int mi = 0; mi < 2; ++mi) {
        int m = wid * 32 + mi * 16 + cl;
        int ch = (kk * 4 + kq) ^ (m & 7);
        a[mi] = *(const short8*)(As + m * 64 + ch * 8);
      }
      #pragma unroll
      for (int ni = 0; ni < 8; ++ni) {
        int n = ni * 16 + cl;
        int ch = (kk * 4 + kq) ^ (n & 7);
        bfr[ni] = *(const short8*)(Bs + n * 64 + ch * 8);
      }
      #pragma unroll
      for (int mi = 0; mi < 2; ++mi)
        #pragma unroll
        for (int ni = 0; ni < 8; ++ni)
          acc[mi][ni] = __builtin_amdgcn_mfma_f32_16x16x32_bf16(
              a[mi], bfr[ni], acc[mi][ni], 0, 0, 0);
    }
    __syncthreads();
  }
  #pragma unroll
  for (int mi = 0; mi < 2; ++mi) {
    #pragma unroll
    for (int ni = 0; ni < 4; ++ni) {
      int o1 = ot * 64 + ni * 16 + cl;
      float b1 = bout[o1], b2 = bout[o1 + 256];
      #pragma unroll
      for (int r = 0; r < 4; ++r) {
        int row = m0 + wid * 32 + mi * 16 + kq * 4 + r;
        float z1 = acc[mi][ni][r] + b1;
        float z2 = acc[mi][ni + 4][r] + b2;
        float g = z1 / (1.f + expf(-z2));
        size_t idx = (size_t)row * Hq + o1;
        hb[idx] = rsrc[idx] + g;
      }
    }
  }
}

extern "C" void kernel_launch(void* const* d_in, const int* in_sizes, int n_in,
                              void* d_out, int out_size, void* d_ws, size_t ws_size,
                              hipStream_t stream) {
  (void)in_sizes; (void)n_in; (void)out_size; (void)ws_size;
  const float* x      = (const float*)d_in[0];
  const float* log_dt = (const float*)d_in[1];
  const float* Alog   = (const float*)d_in[2];
  const float* Aim    = (const float*)d_in[3];
  const float* Cre    = (const float*)d_in[4];
  const float* Cim    = (const float*)d_in[5];
  const float* Dv     = (const float*)d_in[6];
  const float* Wout   = (const float*)d_in[7];
  const float* bout   = (const float*)d_in[8];
  const float* lns    = (const float*)d_in[9];
  const float* lnb    = (const float*)d_in[10];

  float* hb = (float*)d_out;
  float* p  = (float*)d_ws;
  u16* zt  = (u16*)p; p += SZ/2;               // (h, bc, j) bf16
  u16* ytb = (u16*)p; p += SZ/2;               // (h, bc, t) bf16
  u16* ybb = (u16*)p; p += SZ/2;               // (bl, h) bf16
  u16* Vb  = (u16*)p; p += SZ;                 // NL*Hq*128*128 u16
  u16* TRb = (u16*)p; p += 2*SZ;               // NL*Hq*128*256 u16
  u16* Wb  = (u16*)p; p += (NL*2*Hq*Hq)/2;     // bf16 weights, all layers
  float* wLc = p;  p += NL*2*Hq*Nst;

  // params for ALL layers: single kernel
  cvtw_k<<<(NL*2*Hq*Hq)/256, 256, 0, stream>>>(Wout, (__hip_bfloat16*)Wb, NL*2*Hq*Hq);
  param_k<<<NL*Hq, 256, 0, stream>>>(log_dt, Alog, Aim, Cre, Cim, Dv, Vb, TRb, wLc);

  for (int i = 0; i < NL; ++i) {
    const float* src = (i == 0) ? x : hb;
    lntr_k<<<dim3(BC, 2), 512, 0, stream>>>(src, lns + i*Hq, lnb + i*Hq, zt);
    s4core_k<<<dim3(2, Hq), 512, 0, stream>>>(
        zt, Vb + (size_t)i * Hq * 128 * 128, TRb + (size_t)i * Hq * 128 * 256,
        wLc + (size_t)i * 2 * Hq * Nst, ytb);
    trB_k<<<dim3(BC, 4), 256, 0, stream>>>(ytb, ybb);
    gemm_k<<<dim3((Bq*Lq)/128, 4), 256, 0, stream>>>(
        (const __hip_bfloat16*)ybb,
        (const __hip_bfloat16*)(Wb + (size_t)i * 2 * Hq * Hq),
        bout + (size_t)i*2*Hq, src, hb);
  }
}